// Round 1
// baseline (2103.326 us; speedup 1.0000x reference)
//
#include <hip/hip_runtime.h>

static constexpr int K = 128;  // inner dim of both layers (in_ch = hid = 128)

__global__ __launch_bounds__(256) void k_init_deg(float* __restrict__ deg, int n) {
    int i = blockIdx.x * 256 + threadIdx.x;
    if (i < n) deg[i] = 1.0f;  // self-loop
}

__global__ __launch_bounds__(256) void k_count_deg(const int* __restrict__ ei,
                                                   float* __restrict__ deg, int e) {
    int i = blockIdx.x * 256 + threadIdx.x;
    if (i < e) unsafeAtomicAdd(&deg[ei[(size_t)e + i]], 1.0f);  // dst row of edge_index
}

__global__ __launch_bounds__(256) void k_dinv(const float* __restrict__ deg,
                                              float* __restrict__ dinv, int n) {
    int i = blockIdx.x * 256 + threadIdx.x;
    if (i < n) dinv[i] = rsqrtf(deg[i]);  // deg >= 1 always
}

// G = dinv ⊙ (X @ W); also writes ACC = G (self-loop init for the scatter pass).
template <int COUT>
__global__ __launch_bounds__(256) void k_gemm_scale(const float* __restrict__ X,
                                                    const float* __restrict__ W,
                                                    const float* __restrict__ dinv,
                                                    float* __restrict__ G,
                                                    float* __restrict__ ACC, int n) {
    constexpr int CG = COUT / 4;        // float4 col-groups: 32 or 16
    constexpr int SLOTS = 256 / CG;     // row-slots per block: 8 or 16
    constexpr int ROWS = SLOTS * 4;     // rows per block: 32 or 64
    __shared__ __align__(16) float Ws[K * COUT];   // 64 KB or 32 KB
    __shared__ __align__(16) float Xs[ROWS * K];   // 16 KB or 32 KB
    const int tid = threadIdx.x;
    const int row0 = blockIdx.x * ROWS;

    for (int i = tid; i < K * COUT / 4; i += 256)
        ((float4*)Ws)[i] = ((const float4*)W)[i];
    for (int i = tid; i < ROWS * K / 4; i += 256) {
        int r = i / (K / 4), c = i % (K / 4);
        int gr = row0 + r;
        ((float4*)Xs)[i] = (gr < n) ? ((const float4*)(X + (size_t)gr * K))[c]
                                    : make_float4(0.f, 0.f, 0.f, 0.f);
    }
    __syncthreads();

    const int cg = tid % CG;
    const int rsub = (tid / CG) * 4;  // 4 rows per thread
    float4 acc[4];
#pragma unroll
    for (int r = 0; r < 4; ++r) acc[r] = make_float4(0.f, 0.f, 0.f, 0.f);

    for (int k = 0; k < K; ++k) {
        float4 w = ((const float4*)(Ws + k * COUT))[cg];
#pragma unroll
        for (int r = 0; r < 4; ++r) {
            float a = Xs[(rsub + r) * K + k];
            acc[r].x = fmaf(a, w.x, acc[r].x);
            acc[r].y = fmaf(a, w.y, acc[r].y);
            acc[r].z = fmaf(a, w.z, acc[r].z);
            acc[r].w = fmaf(a, w.w, acc[r].w);
        }
    }

#pragma unroll
    for (int r = 0; r < 4; ++r) {
        int gr = row0 + rsub + r;
        if (gr < n) {
            float s = dinv[gr];
            float4 v = acc[r];
            v.x *= s; v.y *= s; v.z *= s; v.w *= s;
            ((float4*)(G + (size_t)gr * COUT))[cg] = v;
            ((float4*)(ACC + (size_t)gr * COUT))[cg] = v;
        }
    }
}

// acc[dst] += g[src] over all edges. COUT/4 lanes per edge, float4 per lane.
template <int COUT>
__global__ __launch_bounds__(256) void k_scatter(const int* __restrict__ ei,
                                                 const float* __restrict__ g,
                                                 float* __restrict__ acc, int e) {
    constexpr int CG = COUT / 4;
    int tid = blockIdx.x * 256 + threadIdx.x;
    int edge = tid / CG;
    int cg = tid % CG;
    if (edge >= e) return;
    int s = ei[edge];
    int d = ei[(size_t)e + edge];
    float4 v = ((const float4*)(g + (size_t)s * COUT))[cg];
    float* a = acc + (size_t)d * COUT + cg * 4;
    unsafeAtomicAdd(a + 0, v.x);
    unsafeAtomicAdd(a + 1, v.y);
    unsafeAtomicAdd(a + 2, v.z);
    unsafeAtomicAdd(a + 3, v.w);
}

// out = (relu?)(dinv ⊙ acc + bias)
template <int COUT, bool RELU>
__global__ __launch_bounds__(256) void k_finish(const float* __restrict__ acc,
                                                const float* __restrict__ dinv,
                                                const float* __restrict__ bias,
                                                float* __restrict__ out, int n) {
    constexpr int CG = COUT / 4;
    int tid = blockIdx.x * 256 + threadIdx.x;
    if (tid >= n * CG) return;
    int row = tid / CG, cg = tid % CG;
    float s = dinv[row];
    float4 v = ((const float4*)(acc + (size_t)row * COUT))[cg];
    float4 b = ((const float4*)bias)[cg];
    float4 o;
    o.x = fmaf(s, v.x, b.x);
    o.y = fmaf(s, v.y, b.y);
    o.z = fmaf(s, v.z, b.z);
    o.w = fmaf(s, v.w, b.w);
    if (RELU) {
        o.x = fmaxf(o.x, 0.f); o.y = fmaxf(o.y, 0.f);
        o.z = fmaxf(o.z, 0.f); o.w = fmaxf(o.w, 0.f);
    }
    ((float4*)(out + (size_t)row * COUT))[cg] = o;
}

extern "C" void kernel_launch(void* const* d_in, const int* in_sizes, int n_in,
                              void* d_out, int out_size, void* d_ws, size_t ws_size,
                              hipStream_t stream) {
    const float* x  = (const float*)d_in[0];
    const int*   ei = (const int*)d_in[1];   // [2, E] int32 (jax x64 disabled)
    const float* W1 = (const float*)d_in[2];
    const float* b1 = (const float*)d_in[3];
    const float* W2 = (const float*)d_in[4];
    const float* b2 = (const float*)d_in[5];
    float* out = (float*)d_out;

    const int n = in_sizes[0] / K;   // 50000
    const int e = in_sizes[1] / 2;   // 800000

    float* ws   = (float*)d_ws;
    float* deg  = ws;                        // n
    float* dinv = deg + n;                   // n
    float* B1   = dinv + n;                  // n*128 : g1, then h(relu)
    float* B2   = B1 + (size_t)n * 128;      // n*128 : acc1, then g2|acc2
    float* g2   = B2;                        // n*64
    float* acc2 = B2 + (size_t)n * 64;       // n*64

    k_init_deg<<<(n + 255) / 256, 256, 0, stream>>>(deg, n);
    k_count_deg<<<(e + 255) / 256, 256, 0, stream>>>(ei, deg, e);
    k_dinv<<<(n + 255) / 256, 256, 0, stream>>>(deg, dinv, n);

    // Layer 1: h = relu(dinv ⊙ (A_hat (dinv ⊙ (x@W1))) + b1)
    k_gemm_scale<128><<<(n + 31) / 32, 256, 0, stream>>>(x, W1, dinv, B1, B2, n);
    k_scatter<128><<<(e * 32 + 255) / 256, 256, 0, stream>>>(ei, B1, B2, e);
    k_finish<128, true><<<(n * 32 + 255) / 256, 256, 0, stream>>>(B2, dinv, b1, B1, n);

    // Layer 2: out = dinv ⊙ (A_hat (dinv ⊙ (h@W2))) + b2
    k_gemm_scale<64><<<(n + 63) / 64, 256, 0, stream>>>(B1, W2, dinv, g2, acc2, n);
    k_scatter<64><<<(e * 16 + 255) / 256, 256, 0, stream>>>(ei, g2, acc2, e);
    k_finish<64, false><<<(n * 16 + 255) / 256, 256, 0, stream>>>(acc2, dinv, b2, out, n);
}

// Round 2
// 366.537 us; speedup vs baseline: 5.7384x; 5.7384x over previous
//
#include <hip/hip_runtime.h>

static constexpr int K = 128;  // inner dim of both layers (in_ch = hid = 128)

// ---------- CSR build ----------

__global__ __launch_bounds__(256) void k_zero_cnt(int* __restrict__ cnt, int n) {
    int i = blockIdx.x * 256 + threadIdx.x;
    if (i < n) cnt[i] = 0;
}

__global__ __launch_bounds__(256) void k_count(const int* __restrict__ ei,
                                               int* __restrict__ cnt, int e) {
    int i = blockIdx.x * 256 + threadIdx.x;
    if (i < e) atomicAdd(&cnt[ei[(size_t)e + i]], 1);  // dst row
}

// per-256-chunk sums
__global__ __launch_bounds__(256) void k_chunk_sum(const int* __restrict__ cnt,
                                                   int* __restrict__ bsum, int n) {
    __shared__ int sh[256];
    int t = threadIdx.x;
    int i = blockIdx.x * 256 + t;
    sh[t] = (i < n) ? cnt[i] : 0;
    __syncthreads();
    for (int o = 128; o > 0; o >>= 1) {
        if (t < o) sh[t] += sh[t + o];
        __syncthreads();
    }
    if (t == 0) bsum[blockIdx.x] = sh[0];
}

// single block: exclusive scan of m chunk sums (m <= 256), in place; offs[n] = total
__global__ __launch_bounds__(256) void k_scan_chunks(int* __restrict__ bsum,
                                                     int* __restrict__ offs, int m, int n) {
    __shared__ int sh[256];
    int t = threadIdx.x;
    int v = (t < m) ? bsum[t] : 0;
    sh[t] = v;
    __syncthreads();
    for (int o = 1; o < 256; o <<= 1) {
        int x = (t >= o) ? sh[t - o] : 0;
        __syncthreads();
        sh[t] += x;
        __syncthreads();
    }
    if (t < m) bsum[t] = sh[t] - v;          // exclusive base per chunk
    if (t == 255) offs[n] = sh[255];         // total (= e)
}

// per-chunk local exclusive scan + base; also dinv and cursor init
__global__ __launch_bounds__(256) void k_local_scan(const int* __restrict__ cnt,
                                                    const int* __restrict__ bsum,
                                                    int* __restrict__ offs,
                                                    int* __restrict__ cursor,
                                                    float* __restrict__ dinv, int n) {
    __shared__ int sh[256];
    int t = threadIdx.x;
    int i = blockIdx.x * 256 + t;
    int v = (i < n) ? cnt[i] : 0;
    sh[t] = v;
    __syncthreads();
    for (int o = 1; o < 256; o <<= 1) {
        int x = (t >= o) ? sh[t - o] : 0;
        __syncthreads();
        sh[t] += x;
        __syncthreads();
    }
    if (i < n) {
        offs[i] = bsum[blockIdx.x] + sh[t] - v;
        cursor[i] = 0;
        dinv[i] = rsqrtf((float)(v + 1));  // deg incl. self-loop
    }
}

__global__ __launch_bounds__(256) void k_fill(const int* __restrict__ ei,
                                              const int* __restrict__ offs,
                                              int* __restrict__ cursor,
                                              int* __restrict__ srt, int e) {
    int i = blockIdx.x * 256 + threadIdx.x;
    if (i >= e) return;
    int s = ei[i];
    int d = ei[(size_t)e + i];
    int pos = offs[d] + atomicAdd(&cursor[d], 1);
    srt[pos] = s;
}

// ---------- G = dinv ⊙ (X @ W) ----------

template <int COUT>
__global__ __launch_bounds__(256) void k_gemm_scale(const float* __restrict__ X,
                                                    const float* __restrict__ W,
                                                    const float* __restrict__ dinv,
                                                    float* __restrict__ G, int n) {
    constexpr int CG = COUT / 4;        // float4 col-groups: 32 or 16
    constexpr int SLOTS = 256 / CG;     // row-slots per block: 8 or 16
    constexpr int ROWS = SLOTS * 4;     // rows per block: 32 or 64
    __shared__ __align__(16) float Ws[K * COUT];
    __shared__ __align__(16) float Xs[ROWS * K];
    const int tid = threadIdx.x;
    const int row0 = blockIdx.x * ROWS;

    for (int i = tid; i < K * COUT / 4; i += 256)
        ((float4*)Ws)[i] = ((const float4*)W)[i];
    for (int i = tid; i < ROWS * K / 4; i += 256) {
        int r = i / (K / 4), c = i % (K / 4);
        int gr = row0 + r;
        ((float4*)Xs)[i] = (gr < n) ? ((const float4*)(X + (size_t)gr * K))[c]
                                    : make_float4(0.f, 0.f, 0.f, 0.f);
    }
    __syncthreads();

    const int cg = tid % CG;
    const int rsub = (tid / CG) * 4;
    float4 acc[4];
#pragma unroll
    for (int r = 0; r < 4; ++r) acc[r] = make_float4(0.f, 0.f, 0.f, 0.f);

    for (int k = 0; k < K; ++k) {
        float4 w = ((const float4*)(Ws + k * COUT))[cg];
#pragma unroll
        for (int r = 0; r < 4; ++r) {
            float a = Xs[(rsub + r) * K + k];
            acc[r].x = fmaf(a, w.x, acc[r].x);
            acc[r].y = fmaf(a, w.y, acc[r].y);
            acc[r].z = fmaf(a, w.z, acc[r].z);
            acc[r].w = fmaf(a, w.w, acc[r].w);
        }
    }

#pragma unroll
    for (int r = 0; r < 4; ++r) {
        int gr = row0 + rsub + r;
        if (gr < n) {
            float s = dinv[gr];
            float4 v = acc[r];
            v.x *= s; v.y *= s; v.z *= s; v.w *= s;
            ((float4*)(G + (size_t)gr * COUT))[cg] = v;
        }
    }
}

// ---------- pull-reduce: out[i] = (relu?)(dinv[i]*(g[i] + sum_{src->i} g[src]) + b) ----------

template <int COUT, bool RELU>
__global__ __launch_bounds__(256) void k_reduce(const int* __restrict__ offs,
                                                const int* __restrict__ srt,
                                                const float* __restrict__ g,
                                                const float* __restrict__ dinv,
                                                const float* __restrict__ bias,
                                                float* __restrict__ out, int n) {
    int node = blockIdx.x * 4 + (threadIdx.x >> 6);  // one wave per node
    if (node >= n) return;
    int lane = threadIdx.x & 63;
    int beg = offs[node], end = offs[node + 1];

    if (COUT == 128) {
        const float2* gp = (const float2*)g;
        float2 a0 = gp[(size_t)node * 64 + lane];    // self-loop term
        float2 a1 = make_float2(0.f, 0.f);
        int j = beg;
        for (; j + 1 < end; j += 2) {
            int s0 = srt[j], s1 = srt[j + 1];
            float2 v0 = gp[(size_t)s0 * 64 + lane];
            float2 v1 = gp[(size_t)s1 * 64 + lane];
            a0.x += v0.x; a0.y += v0.y;
            a1.x += v1.x; a1.y += v1.y;
        }
        if (j < end) {
            float2 v = gp[(size_t)srt[j] * 64 + lane];
            a0.x += v.x; a0.y += v.y;
        }
        float di = dinv[node];
        float2 b = ((const float2*)bias)[lane];
        float2 o;
        o.x = fmaf(di, a0.x + a1.x, b.x);
        o.y = fmaf(di, a0.y + a1.y, b.y);
        if (RELU) { o.x = fmaxf(o.x, 0.f); o.y = fmaxf(o.y, 0.f); }
        ((float2*)out)[(size_t)node * 64 + lane] = o;
    } else {  // COUT == 64
        float a0 = g[(size_t)node * 64 + lane];
        float a1 = 0.f;
        int j = beg;
        for (; j + 1 < end; j += 2) {
            int s0 = srt[j], s1 = srt[j + 1];
            a0 += g[(size_t)s0 * 64 + lane];
            a1 += g[(size_t)s1 * 64 + lane];
        }
        if (j < end) a0 += g[(size_t)srt[j] * 64 + lane];
        float di = dinv[node];
        float o = fmaf(di, a0 + a1, bias[lane]);
        if (RELU) o = fmaxf(o, 0.f);
        out[(size_t)node * 64 + lane] = o;
    }
}

extern "C" void kernel_launch(void* const* d_in, const int* in_sizes, int n_in,
                              void* d_out, int out_size, void* d_ws, size_t ws_size,
                              hipStream_t stream) {
    const float* x  = (const float*)d_in[0];
    const int*   ei = (const int*)d_in[1];   // [2, E] int32
    const float* W1 = (const float*)d_in[2];
    const float* b1 = (const float*)d_in[3];
    const float* W2 = (const float*)d_in[4];
    const float* b2 = (const float*)d_in[5];
    float* out = (float*)d_out;

    const int n = in_sizes[0] / K;   // 50000
    const int e = in_sizes[1] / 2;   // 800000
    const int nchunks = (n + 255) / 256;  // 196

    // workspace layout (all 4B elems; G buffers 16B-aligned)
    int*   cnt    = (int*)d_ws;                    // n
    int*   cursor = cnt + n;                       // n
    int*   offs   = cursor + n;                    // n+1
    int*   bsum   = offs + n + 1;                  // 256
    int*   srt    = bsum + 256;                    // e
    size_t ihead  = (size_t)n * 2 + (n + 1) + 256 + e;
    ihead = (ihead + 3) & ~(size_t)3;
    float* dinv   = (float*)d_ws + ihead;          // n
    size_t fhead  = ihead + n;
    fhead = (fhead + 3) & ~(size_t)3;
    float* G1     = (float*)d_ws + fhead;          // n*128 (also holds h after relu)
    float* G2     = G1 + (size_t)n * 128;          // n*64

    // CSR build + dinv
    k_zero_cnt<<<nchunks, 256, 0, stream>>>(cnt, n);
    k_count<<<(e + 255) / 256, 256, 0, stream>>>(ei, cnt, e);
    k_chunk_sum<<<nchunks, 256, 0, stream>>>(cnt, bsum, n);
    k_scan_chunks<<<1, 256, 0, stream>>>(bsum, offs, nchunks, n);
    k_local_scan<<<nchunks, 256, 0, stream>>>(cnt, bsum, offs, cursor, dinv, n);
    k_fill<<<(e + 255) / 256, 256, 0, stream>>>(ei, offs, cursor, srt, e);

    // Layer 1: h = relu(dinv ⊙ (A_hat (dinv ⊙ (x@W1))) + b1)  [h written over G2's... no: into G1-reuse]
    k_gemm_scale<128><<<(n + 31) / 32, 256, 0, stream>>>(x, W1, dinv, G1, n);
    k_reduce<128, true><<<(n + 3) / 4, 256, 0, stream>>>(offs, srt, G1, dinv, b1, G2, n);
    // NOTE: G2 here temporarily holds h [n*128]? No — h needs n*128 floats; G2 is n*64.
    // Use a dedicated buffer: see H below. (kept inline to preserve 16B alignment)

    // ^ The above call is replaced correctly below; dummy comment retained for clarity.
    (void)0;

    // Layer 2 buffers
    float* H  = G2 + (size_t)n * 64;               // n*128 (relu output)
    float* G2b = H + (size_t)n * 128;              // n*64

    // Redo layer 1 reduce into H (the call above wrote n*128 floats into G2..H region;
    // to keep things simple and correct, just write layer-1 output directly into H):
    // (the first k_reduce call is launched again with the proper destination)
    k_reduce<128, true><<<(n + 3) / 4, 256, 0, stream>>>(offs, srt, G1, dinv, b1, H, n);

    // Layer 2: out = dinv ⊙ (A_hat (dinv ⊙ (h@W2))) + b2
    k_gemm_scale<64><<<(n + 63) / 64, 256, 0, stream>>>(H, W2, dinv, G2b, n);
    k_reduce<64, false><<<(n + 3) / 4, 256, 0, stream>>>(offs, srt, G2b, dinv, b2, out, n);
}

// Round 3
// 237.614 us; speedup vs baseline: 8.8519x; 1.5426x over previous
//
#include <hip/hip_runtime.h>

static constexpr int K = 128;  // inner dim of both layers (in_ch = hid = 128)

__device__ inline float bflo(unsigned u) { return __uint_as_float(u << 16); }
__device__ inline float bfhi(unsigned u) { return __uint_as_float(u & 0xFFFF0000u); }
__device__ inline unsigned short f2bf(float f) {  // round-to-nearest-even
    unsigned u = __float_as_uint(f);
    return (unsigned short)((u + 0x7FFF + ((u >> 16) & 1)) >> 16);
}

// ---------- CSR build ----------

__global__ __launch_bounds__(256) void k_zero_cnt(int* __restrict__ cnt, int n) {
    int i = blockIdx.x * 256 + threadIdx.x;
    if (i < n) cnt[i] = 0;
}

__global__ __launch_bounds__(256) void k_count(const int* __restrict__ ei,
                                               int* __restrict__ cnt, int e) {
    int i = blockIdx.x * 256 + threadIdx.x;
    if (i < e) atomicAdd(&cnt[ei[(size_t)e + i]], 1);  // dst row
}

__global__ __launch_bounds__(256) void k_chunk_sum(const int* __restrict__ cnt,
                                                   int* __restrict__ bsum, int n) {
    __shared__ int sh[256];
    int t = threadIdx.x;
    int i = blockIdx.x * 256 + t;
    sh[t] = (i < n) ? cnt[i] : 0;
    __syncthreads();
    for (int o = 128; o > 0; o >>= 1) {
        if (t < o) sh[t] += sh[t + o];
        __syncthreads();
    }
    if (t == 0) bsum[blockIdx.x] = sh[0];
}

__global__ __launch_bounds__(256) void k_scan_chunks(int* __restrict__ bsum,
                                                     int* __restrict__ offs, int m, int n) {
    __shared__ int sh[256];
    int t = threadIdx.x;
    int v = (t < m) ? bsum[t] : 0;
    sh[t] = v;
    __syncthreads();
    for (int o = 1; o < 256; o <<= 1) {
        int x = (t >= o) ? sh[t - o] : 0;
        __syncthreads();
        sh[t] += x;
        __syncthreads();
    }
    if (t < m) bsum[t] = sh[t] - v;          // exclusive base per chunk
    if (t == 255) offs[n] = sh[255];         // total (= e)
}

__global__ __launch_bounds__(256) void k_local_scan(const int* __restrict__ cnt,
                                                    const int* __restrict__ bsum,
                                                    int* __restrict__ offs,
                                                    int* __restrict__ cursor,
                                                    float* __restrict__ dinv, int n) {
    __shared__ int sh[256];
    int t = threadIdx.x;
    int i = blockIdx.x * 256 + t;
    int v = (i < n) ? cnt[i] : 0;
    sh[t] = v;
    __syncthreads();
    for (int o = 1; o < 256; o <<= 1) {
        int x = (t >= o) ? sh[t - o] : 0;
        __syncthreads();
        sh[t] += x;
        __syncthreads();
    }
    if (i < n) {
        offs[i] = bsum[blockIdx.x] + sh[t] - v;
        cursor[i] = 0;
        dinv[i] = rsqrtf((float)(v + 1));  // deg incl. self-loop
    }
}

__global__ __launch_bounds__(256) void k_fill(const int* __restrict__ ei,
                                              const int* __restrict__ offs,
                                              int* __restrict__ cursor,
                                              int* __restrict__ srt, int e) {
    int i = blockIdx.x * 256 + threadIdx.x;
    if (i >= e) return;
    int s = ei[i];
    int d = ei[(size_t)e + i];
    int pos = offs[d] + atomicAdd(&cursor[d], 1);
    srt[pos] = s;
}

// ---------- G(bf16) = dinv ⊙ (X @ W), X fp32 ----------

template <int COUT>
__global__ __launch_bounds__(256) void k_gemm_scale(const float* __restrict__ X,
                                                    const float* __restrict__ W,
                                                    const float* __restrict__ dinv,
                                                    unsigned short* __restrict__ G, int n) {
    constexpr int CG = COUT / 4;        // float4 col-groups: 32 or 16
    constexpr int SLOTS = 256 / CG;     // row-slots per block: 8 or 16
    constexpr int ROWS = SLOTS * 4;     // rows per block: 32 or 64
    __shared__ __align__(16) float Ws[K * COUT];
    __shared__ __align__(16) float Xs[ROWS * K];
    const int tid = threadIdx.x;
    const int row0 = blockIdx.x * ROWS;

    for (int i = tid; i < K * COUT / 4; i += 256)
        ((float4*)Ws)[i] = ((const float4*)W)[i];
    for (int i = tid; i < ROWS * K / 4; i += 256) {
        int r = i / (K / 4), c = i % (K / 4);
        int gr = row0 + r;
        ((float4*)Xs)[i] = (gr < n) ? ((const float4*)(X + (size_t)gr * K))[c]
                                    : make_float4(0.f, 0.f, 0.f, 0.f);
    }
    __syncthreads();

    const int cg = tid % CG;
    const int rsub = (tid / CG) * 4;
    float4 acc[4];
#pragma unroll
    for (int r = 0; r < 4; ++r) acc[r] = make_float4(0.f, 0.f, 0.f, 0.f);

    for (int k = 0; k < K; ++k) {
        float4 w = ((const float4*)(Ws + k * COUT))[cg];
#pragma unroll
        for (int r = 0; r < 4; ++r) {
            float a = Xs[(rsub + r) * K + k];
            acc[r].x = fmaf(a, w.x, acc[r].x);
            acc[r].y = fmaf(a, w.y, acc[r].y);
            acc[r].z = fmaf(a, w.z, acc[r].z);
            acc[r].w = fmaf(a, w.w, acc[r].w);
        }
    }

#pragma unroll
    for (int r = 0; r < 4; ++r) {
        int gr = row0 + rsub + r;
        if (gr < n) {
            float s = dinv[gr];
            ushort4 o;
            o.x = f2bf(acc[r].x * s);
            o.y = f2bf(acc[r].y * s);
            o.z = f2bf(acc[r].z * s);
            o.w = f2bf(acc[r].w * s);
            ((ushort4*)(G + (size_t)gr * COUT))[cg] = o;
        }
    }
}

// ---------- pull-reduce (bf16 gathers, fp32 accumulate) ----------

// COUT=128: one 64-lane wave per node, 2 bf16 cols per lane (one dword).
template <bool RELU>
__global__ __launch_bounds__(256) void k_reduce128(const int* __restrict__ offs,
                                                   const int* __restrict__ srt,
                                                   const unsigned* __restrict__ g,  // [n][64] dwords
                                                   const float* __restrict__ dinv,
                                                   const float* __restrict__ bias,
                                                   float* __restrict__ out, int n) {
    int node = blockIdx.x * 4 + (threadIdx.x >> 6);
    if (node >= n) return;
    int lane = threadIdx.x & 63;
    int beg = offs[node], end = offs[node + 1];

    unsigned su = g[(size_t)node * 64 + lane];  // self-loop term
    float2 a0 = make_float2(bflo(su), bfhi(su));
    float2 a1 = make_float2(0.f, 0.f);
    int j = beg;
    for (; j + 3 < end; j += 4) {
        int s0 = srt[j], s1 = srt[j + 1], s2 = srt[j + 2], s3 = srt[j + 3];
        unsigned u0 = g[(size_t)s0 * 64 + lane];
        unsigned u1 = g[(size_t)s1 * 64 + lane];
        unsigned u2 = g[(size_t)s2 * 64 + lane];
        unsigned u3 = g[(size_t)s3 * 64 + lane];
        a0.x += bflo(u0); a0.y += bfhi(u0);
        a1.x += bflo(u1); a1.y += bfhi(u1);
        a0.x += bflo(u2); a0.y += bfhi(u2);
        a1.x += bflo(u3); a1.y += bfhi(u3);
    }
    for (; j < end; ++j) {
        unsigned u = g[(size_t)srt[j] * 64 + lane];
        a0.x += bflo(u); a0.y += bfhi(u);
    }
    float di = dinv[node];
    float2 b = ((const float2*)bias)[lane];
    float2 o;
    o.x = fmaf(di, a0.x + a1.x, b.x);
    o.y = fmaf(di, a0.y + a1.y, b.y);
    if (RELU) { o.x = fmaxf(o.x, 0.f); o.y = fmaxf(o.y, 0.f); }
    ((float2*)out)[(size_t)node * 64 + lane] = o;
}

// COUT=64: wave splits into two 32-lane halves, each gathers a different edge
// (full dword/lane), halves combined with one shfl_xor at the end.
template <bool RELU>
__global__ __launch_bounds__(256) void k_reduce64(const int* __restrict__ offs,
                                                  const int* __restrict__ srt,
                                                  const unsigned* __restrict__ g,  // [n][32] dwords
                                                  const float* __restrict__ dinv,
                                                  const float* __restrict__ bias,
                                                  float* __restrict__ out, int n) {
    int node = blockIdx.x * 4 + (threadIdx.x >> 6);
    if (node >= n) return;
    int lane = threadIdx.x & 63;
    int half = lane >> 5, l31 = lane & 31;
    int beg = offs[node], end = offs[node + 1];

    float2 aA = make_float2(0.f, 0.f), aB = make_float2(0.f, 0.f);
    if (half == 0) {  // self-loop term
        unsigned u = g[(size_t)node * 32 + l31];
        aA.x += bflo(u); aA.y += bfhi(u);
    }
    int j = beg;
    for (; j + 3 < end; j += 4) {
        int sA = srt[j + half], sB = srt[j + 2 + half];
        unsigned uA = g[(size_t)sA * 32 + l31];
        unsigned uB = g[(size_t)sB * 32 + l31];
        aA.x += bflo(uA); aA.y += bfhi(uA);
        aB.x += bflo(uB); aB.y += bfhi(uB);
    }
    for (; j + 1 < end; j += 2) {
        int s = srt[j + half];
        unsigned u = g[(size_t)s * 32 + l31];
        aA.x += bflo(u); aA.y += bfhi(u);
    }
    if (j < end && half == 0) {
        unsigned u = g[(size_t)srt[j] * 32 + l31];
        aA.x += bflo(u); aA.y += bfhi(u);
    }
    float2 a = make_float2(aA.x + aB.x, aA.y + aB.y);
    a.x += __shfl_xor(a.x, 32);
    a.y += __shfl_xor(a.y, 32);
    if (half == 0) {
        float di = dinv[node];
        float2 b = ((const float2*)bias)[l31];
        float2 o;
        o.x = fmaf(di, a.x, b.x);
        o.y = fmaf(di, a.y, b.y);
        if (RELU) { o.x = fmaxf(o.x, 0.f); o.y = fmaxf(o.y, 0.f); }
        ((float2*)out)[(size_t)node * 32 + l31] = o;
    }
}

extern "C" void kernel_launch(void* const* d_in, const int* in_sizes, int n_in,
                              void* d_out, int out_size, void* d_ws, size_t ws_size,
                              hipStream_t stream) {
    const float* x  = (const float*)d_in[0];
    const int*   ei = (const int*)d_in[1];   // [2, E] int32
    const float* W1 = (const float*)d_in[2];
    const float* b1 = (const float*)d_in[3];
    const float* W2 = (const float*)d_in[4];
    const float* b2 = (const float*)d_in[5];
    float* out = (float*)d_out;

    const int n = in_sizes[0] / K;   // 50000
    const int e = in_sizes[1] / 2;   // 800000
    const int nchunks = (n + 255) / 256;

    // workspace layout (byte-based, 16B-aligned chunks)
    char* p = (char*)d_ws;
    auto align16 = [](char* q) { return (char*)(((uintptr_t)q + 15) & ~(uintptr_t)15); };
    int* cnt    = (int*)p;            p += (size_t)n * 4;
    int* cursor = (int*)p;            p += (size_t)n * 4;
    int* offs   = (int*)p;            p += (size_t)(n + 1) * 4;
    int* bsum   = (int*)p;            p += 256 * 4;
    int* srt    = (int*)p;            p += (size_t)e * 4;
    p = align16(p);
    float* dinv = (float*)p;          p += (size_t)n * 4;
    p = align16(p);
    unsigned short* G1 = (unsigned short*)p;  p += (size_t)n * 128 * 2;  // bf16 [n][128]
    p = align16(p);
    float* H = (float*)p;             p += (size_t)n * 128 * 4;          // fp32 [n][128]
    p = align16(p);
    unsigned short* G2 = (unsigned short*)p;  p += (size_t)n * 64 * 2;   // bf16 [n][64]

    // CSR build + dinv
    k_zero_cnt<<<nchunks, 256, 0, stream>>>(cnt, n);
    k_count<<<(e + 255) / 256, 256, 0, stream>>>(ei, cnt, e);
    k_chunk_sum<<<nchunks, 256, 0, stream>>>(cnt, bsum, n);
    k_scan_chunks<<<1, 256, 0, stream>>>(bsum, offs, nchunks, n);
    k_local_scan<<<nchunks, 256, 0, stream>>>(cnt, bsum, offs, cursor, dinv, n);
    k_fill<<<(e + 255) / 256, 256, 0, stream>>>(ei, offs, cursor, srt, e);

    // Layer 1: H = relu(dinv ⊙ (A_hat G1) + b1), G1 = dinv ⊙ (x@W1)
    k_gemm_scale<128><<<(n + 31) / 32, 256, 0, stream>>>(x, W1, dinv, G1, n);
    k_reduce128<true><<<(n + 3) / 4, 256, 0, stream>>>(offs, srt, (const unsigned*)G1,
                                                       dinv, b1, H, n);

    // Layer 2: out = dinv ⊙ (A_hat G2) + b2, G2 = dinv ⊙ (H@W2)
    k_gemm_scale<64><<<(n + 63) / 64, 256, 0, stream>>>(H, W2, dinv, G2, n);
    k_reduce64<false><<<(n + 3) / 4, 256, 0, stream>>>(offs, srt, (const unsigned*)G2,
                                                       dinv, b2, out, n);
}

// Round 4
// 190.480 us; speedup vs baseline: 11.0422x; 1.2474x over previous
//
#include <hip/hip_runtime.h>

static constexpr int K = 128;  // inner dim of both layers (in_ch = hid = 128)

__device__ inline float bflo(unsigned u) { return __uint_as_float(u << 16); }
__device__ inline float bfhi(unsigned u) { return __uint_as_float(u & 0xFFFF0000u); }
__device__ inline unsigned short f2bf(float f) {  // round-to-nearest-even
    unsigned u = __float_as_uint(f);
    return (unsigned short)((u + 0x7FFF + ((u >> 16) & 1)) >> 16);
}

// ---------- CSR build via 2-level binned counting sort ----------
// bucket c = dst >> 8 (256 nodes per bucket); bucket regions ARE the final CSR regions.

__global__ __launch_bounds__(256) void k_zerob(int* __restrict__ bcnt) {
    bcnt[threadIdx.x] = 0;
}

// bucket histogram, LDS-aggregated
__global__ __launch_bounds__(256) void k_bcount(const int* __restrict__ dst, int e,
                                                int* __restrict__ bcnt, int nb) {
    __shared__ int c[256];
    int t = threadIdx.x;
    c[t] = 0;
    __syncthreads();
    for (int i = blockIdx.x * 256 + t; i < e; i += gridDim.x * 256)
        atomicAdd(&c[dst[i] >> 8], 1);
    __syncthreads();
    if (t < nb && c[t]) atomicAdd(&bcnt[t], c[t]);
}

// 1 block: exclusive scan of nb bucket counts -> bbase[0..nb], init gcur, offs[n]=e
__global__ __launch_bounds__(256) void k_bscan(const int* __restrict__ bcnt,
                                               int* __restrict__ bbase,
                                               int* __restrict__ gcur,
                                               int nb, int* __restrict__ offs,
                                               int n, int e) {
    __shared__ int sh[256];
    int t = threadIdx.x;
    int v = (t < nb) ? bcnt[t] : 0;
    sh[t] = v;
    __syncthreads();
    for (int o = 1; o < 256; o <<= 1) {
        int x = (t >= o) ? sh[t - o] : 0;
        __syncthreads();
        sh[t] += x;
        __syncthreads();
    }
    int excl = sh[t] - v;
    bbase[t] = excl;        // for t >= nb this equals total e (v=0) — harmless
    gcur[t] = excl;
    if (t == 255) bbase[256] = sh[255];
    if (t == 0) offs[n] = e;
}

// bin (src,dst) pairs into tmp, grouped by bucket; block-contiguous runs per bucket
__global__ __launch_bounds__(256) void k_bin(const int* __restrict__ ei, int e,
                                             int* __restrict__ gcur,
                                             unsigned long long* __restrict__ tmp) {
    constexpr int PER = 16;
    __shared__ int cnt[256], base[256], cur[256];
    int t = threadIdx.x;
    int chunk0 = blockIdx.x * 256 * PER;
    cnt[t] = 0;
    __syncthreads();
    int ds[PER];
#pragma unroll
    for (int k2 = 0; k2 < PER; ++k2) {
        int i = chunk0 + k2 * 256 + t;
        ds[k2] = (i < e) ? ei[(size_t)e + i] : -1;
        if (ds[k2] >= 0) atomicAdd(&cnt[ds[k2] >> 8], 1);
    }
    __syncthreads();
    int c = cnt[t];
    base[t] = c ? atomicAdd(&gcur[t], c) : 0;
    cur[t] = 0;
    __syncthreads();
#pragma unroll
    for (int k2 = 0; k2 < PER; ++k2) {
        int i = chunk0 + k2 * 256 + t;
        if (i < e) {
            int b = ds[k2] >> 8;
            int pos = base[b] + atomicAdd(&cur[b], 1);
            tmp[pos] = ((unsigned long long)(unsigned)ds[k2] << 32) | (unsigned)ei[i];
        }
    }
}

// one block per bucket: per-node counts -> offs/dinv, then place src into srt window
__global__ __launch_bounds__(256) void k_csr(const unsigned long long* __restrict__ tmp,
                                             const int* __restrict__ bbase,
                                             int* __restrict__ offs,
                                             int* __restrict__ srt,
                                             float* __restrict__ dinv, int n) {
    __shared__ int cntS[256], sh[256], cur[256];
    int b = blockIdx.x;
    int t = threadIdx.x;
    int beg = bbase[b], end = bbase[b + 1];
    cntS[t] = 0;
    __syncthreads();
    for (int i = beg + t; i < end; i += 256)
        atomicAdd(&cntS[(int)(tmp[i] >> 32) & 255], 1);
    __syncthreads();
    int v = cntS[t];
    sh[t] = v;
    __syncthreads();
    for (int o = 1; o < 256; o <<= 1) {
        int x = (t >= o) ? sh[t - o] : 0;
        __syncthreads();
        sh[t] += x;
        __syncthreads();
    }
    int pfx = sh[t] - v;
    int node = b * 256 + t;
    if (node < n) {
        offs[node] = beg + pfx;
        dinv[node] = rsqrtf((float)(v + 1));  // deg incl. self-loop
    }
    cur[t] = pfx;
    __syncthreads();
    for (int i = beg + t; i < end; i += 256) {
        unsigned long long pr = tmp[i];
        int d = (int)(pr >> 32);
        int pos = atomicAdd(&cur[d & 255], 1);
        srt[beg + pos] = (int)(pr & 0xFFFFFFFFu);
    }
}

// ---------- G(bf16) = dinv ⊙ (X @ W), X fp32 ----------

template <int COUT>
__global__ __launch_bounds__(256) void k_gemm_scale(const float* __restrict__ X,
                                                    const float* __restrict__ W,
                                                    const float* __restrict__ dinv,
                                                    unsigned short* __restrict__ G, int n) {
    constexpr int CG = COUT / 4;        // float4 col-groups: 32 or 16
    constexpr int SLOTS = 256 / CG;     // row-slots per block: 8 or 16
    constexpr int ROWS = SLOTS * 4;     // rows per block: 32 or 64
    __shared__ __align__(16) float Ws[K * COUT];
    __shared__ __align__(16) float Xs[ROWS * K];
    const int tid = threadIdx.x;
    const int row0 = blockIdx.x * ROWS;

    for (int i = tid; i < K * COUT / 4; i += 256)
        ((float4*)Ws)[i] = ((const float4*)W)[i];
    for (int i = tid; i < ROWS * K / 4; i += 256) {
        int r = i / (K / 4), c = i % (K / 4);
        int gr = row0 + r;
        ((float4*)Xs)[i] = (gr < n) ? ((const float4*)(X + (size_t)gr * K))[c]
                                    : make_float4(0.f, 0.f, 0.f, 0.f);
    }
    __syncthreads();

    const int cg = tid % CG;
    const int rsub = (tid / CG) * 4;
    float4 acc[4];
#pragma unroll
    for (int r = 0; r < 4; ++r) acc[r] = make_float4(0.f, 0.f, 0.f, 0.f);

    for (int k = 0; k < K; ++k) {
        float4 w = ((const float4*)(Ws + k * COUT))[cg];
#pragma unroll
        for (int r = 0; r < 4; ++r) {
            float a = Xs[(rsub + r) * K + k];
            acc[r].x = fmaf(a, w.x, acc[r].x);
            acc[r].y = fmaf(a, w.y, acc[r].y);
            acc[r].z = fmaf(a, w.z, acc[r].z);
            acc[r].w = fmaf(a, w.w, acc[r].w);
        }
    }

#pragma unroll
    for (int r = 0; r < 4; ++r) {
        int gr = row0 + rsub + r;
        if (gr < n) {
            float s = dinv[gr];
            ushort4 o;
            o.x = f2bf(acc[r].x * s);
            o.y = f2bf(acc[r].y * s);
            o.z = f2bf(acc[r].z * s);
            o.w = f2bf(acc[r].w * s);
            ((ushort4*)(G + (size_t)gr * COUT))[cg] = o;
        }
    }
}

// ---------- pull-reduce (bf16 gathers, fp32 accumulate) ----------

template <bool RELU>
__global__ __launch_bounds__(256) void k_reduce128(const int* __restrict__ offs,
                                                   const int* __restrict__ srt,
                                                   const unsigned* __restrict__ g,  // [n][64] dwords
                                                   const float* __restrict__ dinv,
                                                   const float* __restrict__ bias,
                                                   float* __restrict__ out, int n) {
    int node = blockIdx.x * 4 + (threadIdx.x >> 6);
    if (node >= n) return;
    int lane = threadIdx.x & 63;
    int beg = offs[node], end = offs[node + 1];

    unsigned su = g[(size_t)node * 64 + lane];  // self-loop term
    float2 a0 = make_float2(bflo(su), bfhi(su));
    float2 a1 = make_float2(0.f, 0.f);
    int j = beg;
    for (; j + 3 < end; j += 4) {
        int s0 = srt[j], s1 = srt[j + 1], s2 = srt[j + 2], s3 = srt[j + 3];
        unsigned u0 = g[(size_t)s0 * 64 + lane];
        unsigned u1 = g[(size_t)s1 * 64 + lane];
        unsigned u2 = g[(size_t)s2 * 64 + lane];
        unsigned u3 = g[(size_t)s3 * 64 + lane];
        a0.x += bflo(u0); a0.y += bfhi(u0);
        a1.x += bflo(u1); a1.y += bfhi(u1);
        a0.x += bflo(u2); a0.y += bfhi(u2);
        a1.x += bflo(u3); a1.y += bfhi(u3);
    }
    for (; j < end; ++j) {
        unsigned u = g[(size_t)srt[j] * 64 + lane];
        a0.x += bflo(u); a0.y += bfhi(u);
    }
    float di = dinv[node];
    float2 b = ((const float2*)bias)[lane];
    float2 o;
    o.x = fmaf(di, a0.x + a1.x, b.x);
    o.y = fmaf(di, a0.y + a1.y, b.y);
    if (RELU) { o.x = fmaxf(o.x, 0.f); o.y = fmaxf(o.y, 0.f); }
    ((float2*)out)[(size_t)node * 64 + lane] = o;
}

template <bool RELU>
__global__ __launch_bounds__(256) void k_reduce64(const int* __restrict__ offs,
                                                  const int* __restrict__ srt,
                                                  const unsigned* __restrict__ g,  // [n][32] dwords
                                                  const float* __restrict__ dinv,
                                                  const float* __restrict__ bias,
                                                  float* __restrict__ out, int n) {
    int node = blockIdx.x * 4 + (threadIdx.x >> 6);
    if (node >= n) return;
    int lane = threadIdx.x & 63;
    int half = lane >> 5, l31 = lane & 31;
    int beg = offs[node], end = offs[node + 1];

    float2 aA = make_float2(0.f, 0.f), aB = make_float2(0.f, 0.f);
    if (half == 0) {  // self-loop term
        unsigned u = g[(size_t)node * 32 + l31];
        aA.x += bflo(u); aA.y += bfhi(u);
    }
    int j = beg;
    for (; j + 3 < end; j += 4) {
        int sA = srt[j + half], sB = srt[j + 2 + half];
        unsigned uA = g[(size_t)sA * 32 + l31];
        unsigned uB = g[(size_t)sB * 32 + l31];
        aA.x += bflo(uA); aA.y += bfhi(uA);
        aB.x += bflo(uB); aB.y += bfhi(uB);
    }
    for (; j + 1 < end; j += 2) {
        int s = srt[j + half];
        unsigned u = g[(size_t)s * 32 + l31];
        aA.x += bflo(u); aA.y += bfhi(u);
    }
    if (j < end && half == 0) {
        unsigned u = g[(size_t)srt[j] * 32 + l31];
        aA.x += bflo(u); aA.y += bfhi(u);
    }
    float2 a = make_float2(aA.x + aB.x, aA.y + aB.y);
    a.x += __shfl_xor(a.x, 32);
    a.y += __shfl_xor(a.y, 32);
    if (half == 0) {
        float di = dinv[node];
        float2 b = ((const float2*)bias)[l31];
        float2 o;
        o.x = fmaf(di, a.x, b.x);
        o.y = fmaf(di, a.y, b.y);
        if (RELU) { o.x = fmaxf(o.x, 0.f); o.y = fmaxf(o.y, 0.f); }
        ((float2*)out)[(size_t)node * 32 + l31] = o;
    }
}

extern "C" void kernel_launch(void* const* d_in, const int* in_sizes, int n_in,
                              void* d_out, int out_size, void* d_ws, size_t ws_size,
                              hipStream_t stream) {
    const float* x  = (const float*)d_in[0];
    const int*   ei = (const int*)d_in[1];   // [2, E] int32
    const float* W1 = (const float*)d_in[2];
    const float* b1 = (const float*)d_in[3];
    const float* W2 = (const float*)d_in[4];
    const float* b2 = (const float*)d_in[5];
    float* out = (float*)d_out;

    const int n = in_sizes[0] / K;   // 50000
    const int e = in_sizes[1] / 2;   // 800000
    const int nb = (n + 255) / 256;  // 196 buckets

    // workspace layout (8B-aligned head first)
    char* p = (char*)d_ws;
    unsigned long long* tmp = (unsigned long long*)p;  p += (size_t)e * 8;  // (dst,src) pairs
    int* bcnt  = (int*)p;  p += 256 * 4;
    int* bbase = (int*)p;  p += 257 * 4;
    int* gcur  = (int*)p;  p += 256 * 4;
    int* offs  = (int*)p;  p += (size_t)(n + 1) * 4;
    int* srt   = (int*)p;  p += (size_t)e * 4;
    float* dinv = (float*)p;  p += (size_t)n * 4;
    p = (char*)(((uintptr_t)p + 15) & ~(uintptr_t)15);
    unsigned short* G1 = (unsigned short*)p;  p += (size_t)n * 128 * 2;  // bf16 [n][128]
    p = (char*)(((uintptr_t)p + 15) & ~(uintptr_t)15);
    float* H = (float*)p;  p += (size_t)n * 128 * 4;                     // fp32 [n][128]
    p = (char*)(((uintptr_t)p + 15) & ~(uintptr_t)15);
    unsigned short* G2 = (unsigned short*)p;                             // bf16 [n][64]

    // CSR build
    k_zerob<<<1, 256, 0, stream>>>(bcnt);
    k_bcount<<<512, 256, 0, stream>>>(ei + e, e, bcnt, nb);
    k_bscan<<<1, 256, 0, stream>>>(bcnt, bbase, gcur, nb, offs, n, e);
    k_bin<<<(e + 4095) / 4096, 256, 0, stream>>>(ei, e, gcur, tmp);
    k_csr<<<nb, 256, 0, stream>>>(tmp, bbase, offs, srt, dinv, n);

    // Layer 1: H = relu(dinv ⊙ (A_hat G1) + b1), G1 = dinv ⊙ (x@W1)
    k_gemm_scale<128><<<(n + 31) / 32, 256, 0, stream>>>(x, W1, dinv, G1, n);
    k_reduce128<true><<<(n + 3) / 4, 256, 0, stream>>>(offs, srt, (const unsigned*)G1,
                                                       dinv, b1, H, n);

    // Layer 2: out = dinv ⊙ (A_hat G2) + b2, G2 = dinv ⊙ (H@W2)
    k_gemm_scale<64><<<(n + 63) / 64, 256, 0, stream>>>(H, W2, dinv, G2, n);
    k_reduce64<false><<<(n + 3) / 4, 256, 0, stream>>>(offs, srt, (const unsigned*)G2,
                                                       dinv, b2, out, n);
}

// Round 5
// 185.328 us; speedup vs baseline: 11.3492x; 1.0278x over previous
//
#include <hip/hip_runtime.h>

static constexpr int K = 128;  // inner dim of both layers (in_ch = hid = 128)

using ushort8 = __attribute__((ext_vector_type(8))) unsigned short;

__device__ inline float bflo(unsigned u) { return __uint_as_float(u << 16); }
__device__ inline float bfhi(unsigned u) { return __uint_as_float(u & 0xFFFF0000u); }
__device__ inline unsigned short f2bf(float f) {  // round-to-nearest-even
    unsigned u = __float_as_uint(f);
    return (unsigned short)((u + 0x7FFF + ((u >> 16) & 1)) >> 16);
}

// ---------- CSR build via 2-level binned counting sort ----------
// bucket c = dst >> 8 (256 nodes per bucket); bucket regions ARE the final CSR regions.

__global__ __launch_bounds__(256) void k_zerob(int* __restrict__ bcnt) {
    bcnt[threadIdx.x] = 0;
}

__global__ __launch_bounds__(256) void k_bcount(const int* __restrict__ dst, int e,
                                                int* __restrict__ bcnt, int nb) {
    __shared__ int c[256];
    int t = threadIdx.x;
    c[t] = 0;
    __syncthreads();
    for (int i = blockIdx.x * 256 + t; i < e; i += gridDim.x * 256)
        atomicAdd(&c[dst[i] >> 8], 1);
    __syncthreads();
    if (t < nb && c[t]) atomicAdd(&bcnt[t], c[t]);
}

__global__ __launch_bounds__(256) void k_bscan(const int* __restrict__ bcnt,
                                               int* __restrict__ bbase,
                                               int* __restrict__ gcur,
                                               int nb, int* __restrict__ offs,
                                               int n, int e) {
    __shared__ int sh[256];
    int t = threadIdx.x;
    int v = (t < nb) ? bcnt[t] : 0;
    sh[t] = v;
    __syncthreads();
    for (int o = 1; o < 256; o <<= 1) {
        int x = (t >= o) ? sh[t - o] : 0;
        __syncthreads();
        sh[t] += x;
        __syncthreads();
    }
    int excl = sh[t] - v;
    bbase[t] = excl;
    gcur[t] = excl;
    if (t == 255) bbase[256] = sh[255];
    if (t == 0) offs[n] = e;
}

__global__ __launch_bounds__(256) void k_bin(const int* __restrict__ ei, int e,
                                             int* __restrict__ gcur,
                                             unsigned long long* __restrict__ tmp) {
    constexpr int PER = 16;
    __shared__ int cnt[256], base[256], cur[256];
    int t = threadIdx.x;
    int chunk0 = blockIdx.x * 256 * PER;
    cnt[t] = 0;
    __syncthreads();
    int ds[PER];
#pragma unroll
    for (int k2 = 0; k2 < PER; ++k2) {
        int i = chunk0 + k2 * 256 + t;
        ds[k2] = (i < e) ? ei[(size_t)e + i] : -1;
        if (ds[k2] >= 0) atomicAdd(&cnt[ds[k2] >> 8], 1);
    }
    __syncthreads();
    int c = cnt[t];
    base[t] = c ? atomicAdd(&gcur[t], c) : 0;
    cur[t] = 0;
    __syncthreads();
#pragma unroll
    for (int k2 = 0; k2 < PER; ++k2) {
        int i = chunk0 + k2 * 256 + t;
        if (i < e) {
            int b = ds[k2] >> 8;
            int pos = base[b] + atomicAdd(&cur[b], 1);
            tmp[pos] = ((unsigned long long)(unsigned)ds[k2] << 32) | (unsigned)ei[i];
        }
    }
}

__global__ __launch_bounds__(256) void k_csr(const unsigned long long* __restrict__ tmp,
                                             const int* __restrict__ bbase,
                                             int* __restrict__ offs,
                                             int* __restrict__ srt,
                                             float* __restrict__ dinv, int n) {
    __shared__ int cntS[256], sh[256], cur[256];
    int b = blockIdx.x;
    int t = threadIdx.x;
    int beg = bbase[b], end = bbase[b + 1];
    cntS[t] = 0;
    __syncthreads();
    for (int i = beg + t; i < end; i += 256)
        atomicAdd(&cntS[(int)(tmp[i] >> 32) & 255], 1);
    __syncthreads();
    int v = cntS[t];
    sh[t] = v;
    __syncthreads();
    for (int o = 1; o < 256; o <<= 1) {
        int x = (t >= o) ? sh[t - o] : 0;
        __syncthreads();
        sh[t] += x;
        __syncthreads();
    }
    int pfx = sh[t] - v;
    int node = b * 256 + t;
    if (node < n) {
        offs[node] = beg + pfx;
        dinv[node] = rsqrtf((float)(v + 1));  // deg incl. self-loop
    }
    cur[t] = pfx;
    __syncthreads();
    for (int i = beg + t; i < end; i += 256) {
        unsigned long long pr = tmp[i];
        int d = (int)(pr >> 32);
        int pos = atomicAdd(&cur[d & 255], 1);
        srt[beg + pos] = (int)(pr & 0xFFFFFFFFu);
    }
}

// ---------- G(bf16) = dinv ⊙ (X @ W); register-tiled fp32 vector GEMM ----------
// Block: 256 threads, BM x COUT tile, K chunked by 32. Each thread: 4 rows x 8 cols.
// Xs padded to 36 floats/row -> 2-way (free) on x-reads.
// Ws skewed: 8-col group g stored at g*8 + 4*(g>>2) -> 2-way (128) / conflict-free (64).

template <int COUT>
__global__ __launch_bounds__(256) void k_gemm_scale(const float* __restrict__ X,
                                                    const float* __restrict__ W,
                                                    const float* __restrict__ dinv,
                                                    unsigned short* __restrict__ G, int n) {
    constexpr int BM = 8192 / COUT;                     // 64 | 128
    constexpr int BK = 32;
    constexpr int XP = BK + 4;                          // 36
    constexpr int WP = COUT + ((COUT == 128) ? 12 : 4); // 140 | 68
    constexpr int CGRP = COUT / 8;                      // 16 | 8
    __shared__ float Xs[BM * XP];
    __shared__ float Ws[BK * WP];
    const int tid = threadIdx.x;
    const int row0 = blockIdx.x * BM;
    const int tc = tid % CGRP;
    const int tr = tid / CGRP;
    const int c0g = tc * 8 + ((tc >> 2) << 2);  // skewed LDS col offset
    const int c0 = tc * 8;                      // true col
    const int r0 = tr * 4;

    float acc[4][8] = {};

    for (int k0 = 0; k0 < K; k0 += BK) {
        for (int i = tid; i < BK * COUT / 4; i += 256) {
            int kk = i / (COUT / 4), cc = i % (COUT / 4);
            int g = cc >> 1;
            int off = g * 8 + ((g >> 2) << 2) + (cc & 1) * 4;
            *(float4*)&Ws[kk * WP + off] =
                ((const float4*)(W + (size_t)(k0 + kk) * COUT))[cc];
        }
        for (int i = tid; i < BM * BK / 4; i += 256) {
            int r = i / (BK / 4), cc = i % (BK / 4);
            int gr = row0 + r;
            float4 v = make_float4(0.f, 0.f, 0.f, 0.f);
            if (gr < n) v = ((const float4*)(X + (size_t)gr * K + k0))[cc];
            *(float4*)&Xs[r * XP + cc * 4] = v;
        }
        __syncthreads();
#pragma unroll
        for (int kk = 0; kk < BK; kk += 4) {
            float4 xv[4];
#pragma unroll
            for (int r = 0; r < 4; ++r)
                xv[r] = *(const float4*)&Xs[(r0 + r) * XP + kk];
#pragma unroll
            for (int j = 0; j < 4; ++j) {
                float4 w0 = *(const float4*)&Ws[(kk + j) * WP + c0g];
                float4 w1 = *(const float4*)&Ws[(kk + j) * WP + c0g + 4];
#pragma unroll
                for (int r = 0; r < 4; ++r) {
                    float a = ((const float*)&xv[r])[j];
                    acc[r][0] = fmaf(a, w0.x, acc[r][0]);
                    acc[r][1] = fmaf(a, w0.y, acc[r][1]);
                    acc[r][2] = fmaf(a, w0.z, acc[r][2]);
                    acc[r][3] = fmaf(a, w0.w, acc[r][3]);
                    acc[r][4] = fmaf(a, w1.x, acc[r][4]);
                    acc[r][5] = fmaf(a, w1.y, acc[r][5]);
                    acc[r][6] = fmaf(a, w1.z, acc[r][6]);
                    acc[r][7] = fmaf(a, w1.w, acc[r][7]);
                }
            }
        }
        __syncthreads();
    }

#pragma unroll
    for (int r = 0; r < 4; ++r) {
        int gr = row0 + r0 + r;
        if (gr < n) {
            float s = dinv[gr];
            ushort8 o;
#pragma unroll
            for (int j = 0; j < 8; ++j) o[j] = f2bf(acc[r][j] * s);
            *(ushort8*)(G + (size_t)gr * COUT + c0) = o;
        }
    }
}

// ---------- pull-reduce (bf16 gathers, fp32 accumulate) ----------

template <bool RELU>
__global__ __launch_bounds__(256) void k_reduce128(const int* __restrict__ offs,
                                                   const int* __restrict__ srt,
                                                   const unsigned* __restrict__ g,  // [n][64] dwords
                                                   const float* __restrict__ dinv,
                                                   const float* __restrict__ bias,
                                                   float* __restrict__ out, int n) {
    int node = blockIdx.x * 4 + (threadIdx.x >> 6);
    if (node >= n) return;
    int lane = threadIdx.x & 63;
    int beg = offs[node], end = offs[node + 1];

    unsigned su = g[(size_t)node * 64 + lane];  // self-loop term
    float2 a0 = make_float2(bflo(su), bfhi(su));
    float2 a1 = make_float2(0.f, 0.f);
    int j = beg;
    for (; j + 3 < end; j += 4) {
        int s0 = srt[j], s1 = srt[j + 1], s2 = srt[j + 2], s3 = srt[j + 3];
        unsigned u0 = g[(size_t)s0 * 64 + lane];
        unsigned u1 = g[(size_t)s1 * 64 + lane];
        unsigned u2 = g[(size_t)s2 * 64 + lane];
        unsigned u3 = g[(size_t)s3 * 64 + lane];
        a0.x += bflo(u0); a0.y += bfhi(u0);
        a1.x += bflo(u1); a1.y += bfhi(u1);
        a0.x += bflo(u2); a0.y += bfhi(u2);
        a1.x += bflo(u3); a1.y += bfhi(u3);
    }
    for (; j < end; ++j) {
        unsigned u = g[(size_t)srt[j] * 64 + lane];
        a0.x += bflo(u); a0.y += bfhi(u);
    }
    float di = dinv[node];
    float2 b = ((const float2*)bias)[lane];
    float2 o;
    o.x = fmaf(di, a0.x + a1.x, b.x);
    o.y = fmaf(di, a0.y + a1.y, b.y);
    if (RELU) { o.x = fmaxf(o.x, 0.f); o.y = fmaxf(o.y, 0.f); }
    ((float2*)out)[(size_t)node * 64 + lane] = o;
}

template <bool RELU>
__global__ __launch_bounds__(256) void k_reduce64(const int* __restrict__ offs,
                                                  const int* __restrict__ srt,
                                                  const unsigned* __restrict__ g,  // [n][32] dwords
                                                  const float* __restrict__ dinv,
                                                  const float* __restrict__ bias,
                                                  float* __restrict__ out, int n) {
    int node = blockIdx.x * 4 + (threadIdx.x >> 6);
    if (node >= n) return;
    int lane = threadIdx.x & 63;
    int half = lane >> 5, l31 = lane & 31;
    int beg = offs[node], end = offs[node + 1];

    float2 aA = make_float2(0.f, 0.f), aB = make_float2(0.f, 0.f);
    if (half == 0) {  // self-loop term
        unsigned u = g[(size_t)node * 32 + l31];
        aA.x += bflo(u); aA.y += bfhi(u);
    }
    int j = beg;
    for (; j + 3 < end; j += 4) {
        int sA = srt[j + half], sB = srt[j + 2 + half];
        unsigned uA = g[(size_t)sA * 32 + l31];
        unsigned uB = g[(size_t)sB * 32 + l31];
        aA.x += bflo(uA); aA.y += bfhi(uA);
        aB.x += bflo(uB); aB.y += bfhi(uB);
    }
    for (; j + 1 < end; j += 2) {
        int s = srt[j + half];
        unsigned u = g[(size_t)s * 32 + l31];
        aA.x += bflo(u); aA.y += bfhi(u);
    }
    if (j < end && half == 0) {
        unsigned u = g[(size_t)srt[j] * 32 + l31];
        aA.x += bflo(u); aA.y += bfhi(u);
    }
    float2 a = make_float2(aA.x + aB.x, aA.y + aB.y);
    a.x += __shfl_xor(a.x, 32);
    a.y += __shfl_xor(a.y, 32);
    if (half == 0) {
        float di = dinv[node];
        float2 b = ((const float2*)bias)[l31];
        float2 o;
        o.x = fmaf(di, a.x, b.x);
        o.y = fmaf(di, a.y, b.y);
        if (RELU) { o.x = fmaxf(o.x, 0.f); o.y = fmaxf(o.y, 0.f); }
        ((float2*)out)[(size_t)node * 32 + l31] = o;
    }
}

extern "C" void kernel_launch(void* const* d_in, const int* in_sizes, int n_in,
                              void* d_out, int out_size, void* d_ws, size_t ws_size,
                              hipStream_t stream) {
    const float* x  = (const float*)d_in[0];
    const int*   ei = (const int*)d_in[1];   // [2, E] int32
    const float* W1 = (const float*)d_in[2];
    const float* b1 = (const float*)d_in[3];
    const float* W2 = (const float*)d_in[4];
    const float* b2 = (const float*)d_in[5];
    float* out = (float*)d_out;

    const int n = in_sizes[0] / K;   // 50000
    const int e = in_sizes[1] / 2;   // 800000
    const int nb = (n + 255) / 256;  // 196 buckets

    // workspace layout (8B-aligned head first)
    char* p = (char*)d_ws;
    unsigned long long* tmp = (unsigned long long*)p;  p += (size_t)e * 8;  // (dst,src) pairs
    int* bcnt  = (int*)p;  p += 256 * 4;
    int* bbase = (int*)p;  p += 257 * 4;
    int* gcur  = (int*)p;  p += 256 * 4;
    int* offs  = (int*)p;  p += (size_t)(n + 1) * 4;
    int* srt   = (int*)p;  p += (size_t)e * 4;
    float* dinv = (float*)p;  p += (size_t)n * 4;
    p = (char*)(((uintptr_t)p + 15) & ~(uintptr_t)15);
    unsigned short* G1 = (unsigned short*)p;  p += (size_t)n * 128 * 2;  // bf16 [n][128]
    p = (char*)(((uintptr_t)p + 15) & ~(uintptr_t)15);
    float* H = (float*)p;  p += (size_t)n * 128 * 4;                     // fp32 [n][128]
    p = (char*)(((uintptr_t)p + 15) & ~(uintptr_t)15);
    unsigned short* G2 = (unsigned short*)p;                             // bf16 [n][64]

    // CSR build
    k_zerob<<<1, 256, 0, stream>>>(bcnt);
    k_bcount<<<512, 256, 0, stream>>>(ei + e, e, bcnt, nb);
    k_bscan<<<1, 256, 0, stream>>>(bcnt, bbase, gcur, nb, offs, n, e);
    k_bin<<<(e + 4095) / 4096, 256, 0, stream>>>(ei, e, gcur, tmp);
    k_csr<<<nb, 256, 0, stream>>>(tmp, bbase, offs, srt, dinv, n);

    // Layer 1: H = relu(dinv ⊙ (A_hat G1) + b1), G1 = dinv ⊙ (x@W1)
    k_gemm_scale<128><<<(n + 63) / 64, 256, 0, stream>>>(x, W1, dinv, G1, n);
    k_reduce128<true><<<(n + 3) / 4, 256, 0, stream>>>(offs, srt, (const unsigned*)G1,
                                                       dinv, b1, H, n);

    // Layer 2: out = dinv ⊙ (A_hat G2) + b2, G2 = dinv ⊙ (H@W2)
    k_gemm_scale<64><<<(n + 127) / 128, 256, 0, stream>>>(H, W2, dinv, G2, n);
    k_reduce64<false><<<(n + 3) / 4, 256, 0, stream>>>(offs, srt, (const unsigned*)G2,
                                                       dinv, b2, out, n);
}

// Round 6
// 175.577 us; speedup vs baseline: 11.9795x; 1.0555x over previous
//
#include <hip/hip_runtime.h>

static constexpr int K = 128;  // inner dim of both layers (in_ch = hid = 128)

using ushort8 = __attribute__((ext_vector_type(8))) unsigned short;

__device__ inline float bflo(unsigned u) { return __uint_as_float(u << 16); }
__device__ inline float bfhi(unsigned u) { return __uint_as_float(u & 0xFFFF0000u); }
__device__ inline unsigned short f2bf(float f) {  // round-to-nearest-even
    unsigned u = __float_as_uint(f);
    return (unsigned short)((u + 0x7FFF + ((u >> 16) & 1)) >> 16);
}

// ---------- CSR build via 2-level binned counting sort ----------
// bucket c = dst >> 8 (256 nodes per bucket); bucket regions ARE the final CSR regions.

__global__ __launch_bounds__(256) void k_zerob(int* __restrict__ bcnt) {
    bcnt[threadIdx.x] = 0;
}

__global__ __launch_bounds__(256) void k_bcount(const int* __restrict__ dst, int e,
                                                int* __restrict__ bcnt, int nb) {
    __shared__ int c[256];
    int t = threadIdx.x;
    c[t] = 0;
    __syncthreads();
    for (int i = blockIdx.x * 256 + t; i < e; i += gridDim.x * 256)
        atomicAdd(&c[dst[i] >> 8], 1);
    __syncthreads();
    if (t < nb && c[t]) atomicAdd(&bcnt[t], c[t]);
}

__global__ __launch_bounds__(256) void k_bscan(const int* __restrict__ bcnt,
                                               int* __restrict__ bbase,
                                               int* __restrict__ gcur,
                                               int nb, int* __restrict__ offs,
                                               int n, int e) {
    __shared__ int sh[256];
    int t = threadIdx.x;
    int v = (t < nb) ? bcnt[t] : 0;
    sh[t] = v;
    __syncthreads();
    for (int o = 1; o < 256; o <<= 1) {
        int x = (t >= o) ? sh[t - o] : 0;
        __syncthreads();
        sh[t] += x;
        __syncthreads();
    }
    int excl = sh[t] - v;
    bbase[t] = excl;
    gcur[t] = excl;
    if (t == 255) bbase[256] = sh[255];
    if (t == 0) offs[n] = e;
}

__global__ __launch_bounds__(256) void k_bin(const int* __restrict__ ei, int e,
                                             int* __restrict__ gcur,
                                             unsigned long long* __restrict__ tmp) {
    constexpr int PER = 8;
    __shared__ int cnt[256], base[256], cur[256];
    int t = threadIdx.x;
    int chunk0 = blockIdx.x * 256 * PER;
    cnt[t] = 0;
    __syncthreads();
    int ds[PER];
#pragma unroll
    for (int k2 = 0; k2 < PER; ++k2) {
        int i = chunk0 + k2 * 256 + t;
        ds[k2] = (i < e) ? ei[(size_t)e + i] : -1;
        if (ds[k2] >= 0) atomicAdd(&cnt[ds[k2] >> 8], 1);
    }
    __syncthreads();
    int c = cnt[t];
    base[t] = c ? atomicAdd(&gcur[t], c) : 0;
    cur[t] = 0;
    __syncthreads();
#pragma unroll
    for (int k2 = 0; k2 < PER; ++k2) {
        int i = chunk0 + k2 * 256 + t;
        if (i < e) {
            int b = ds[k2] >> 8;
            int pos = base[b] + atomicAdd(&cur[b], 1);
            tmp[pos] = ((unsigned long long)(unsigned)ds[k2] << 32) | (unsigned)ei[i];
        }
    }
}

__global__ __launch_bounds__(256) void k_csr(const unsigned long long* __restrict__ tmp,
                                             const int* __restrict__ bbase,
                                             int* __restrict__ offs,
                                             int* __restrict__ srt,
                                             float* __restrict__ dinv, int n) {
    __shared__ int cntS[256], sh[256], cur[256];
    int b = blockIdx.x;
    int t = threadIdx.x;
    int beg = bbase[b], end = bbase[b + 1];
    cntS[t] = 0;
    __syncthreads();
    for (int i = beg + t; i < end; i += 256)
        atomicAdd(&cntS[(int)(tmp[i] >> 32) & 255], 1);
    __syncthreads();
    int v = cntS[t];
    sh[t] = v;
    __syncthreads();
    for (int o = 1; o < 256; o <<= 1) {
        int x = (t >= o) ? sh[t - o] : 0;
        __syncthreads();
        sh[t] += x;
        __syncthreads();
    }
    int pfx = sh[t] - v;
    int node = b * 256 + t;
    if (node < n) {
        offs[node] = beg + pfx;
        dinv[node] = rsqrtf((float)(v + 1));  // deg incl. self-loop
    }
    cur[t] = pfx;
    __syncthreads();
    for (int i = beg + t; i < end; i += 256) {
        unsigned long long pr = tmp[i];
        int d = (int)(pr >> 32);
        int pos = atomicAdd(&cur[d & 255], 1);
        srt[beg + pos] = (int)(pr & 0xFFFFFFFFu);
    }
}

// ---------- G(bf16) = dinv ⊙ (X @ W); double-buffered register-tiled fp32 GEMM ----------
// BK=16 chunks; global loads for chunk c+1 issued before computing chunk c (regs),
// ds_write into the inactive buffer, ONE barrier per chunk.

template <int COUT>
__global__ __launch_bounds__(256) void k_gemm_scale(const float* __restrict__ X,
                                                    const float* __restrict__ W,
                                                    const float* __restrict__ dinv,
                                                    unsigned short* __restrict__ G, int n) {
    constexpr int BM = 8192 / COUT;                     // 64 | 128
    constexpr int BK = 16;
    constexpr int XP = BK + 4;                          // 20
    constexpr int WP = COUT + ((COUT == 128) ? 12 : 4); // 140 | 68
    constexpr int CGRP = COUT / 8;                      // 16 | 8
    constexpr int NW = BK * COUT / 4 / 256;             // 2 | 1
    constexpr int NX = BM * BK / 4 / 256;               // 1 | 2
    constexpr int NCH = K / BK;                         // 8
    __shared__ float Xs[2][BM * XP];
    __shared__ float Ws[2][BK * WP];
    const int tid = threadIdx.x;
    const int row0 = blockIdx.x * BM;
    const int tc = tid % CGRP;
    const int tr = tid / CGRP;
    const int c0g = tc * 8 + ((tc >> 2) << 2);  // skewed LDS col offset
    const int c0 = tc * 8;                      // true col
    const int r0 = tr * 4;

    float4 wreg[NW], xreg[NX];

    auto loadRegs = [&](int k0) {
#pragma unroll
        for (int q = 0; q < NW; ++q) {
            int i = tid + q * 256;
            int kk = i / (COUT / 4), cc = i % (COUT / 4);
            wreg[q] = ((const float4*)(W + (size_t)(k0 + kk) * COUT))[cc];
        }
#pragma unroll
        for (int q = 0; q < NX; ++q) {
            int i = tid + q * 256;
            int r = i / (BK / 4), cc = i % (BK / 4);
            int gr = row0 + r;
            xreg[q] = (gr < n) ? ((const float4*)(X + (size_t)gr * K + k0))[cc]
                               : make_float4(0.f, 0.f, 0.f, 0.f);
        }
    };
    auto writeLDS = [&](int b) {
#pragma unroll
        for (int q = 0; q < NW; ++q) {
            int i = tid + q * 256;
            int kk = i / (COUT / 4), cc = i % (COUT / 4);
            int g = cc >> 1;
            int off = g * 8 + ((g >> 2) << 2) + (cc & 1) * 4;
            *(float4*)&Ws[b][kk * WP + off] = wreg[q];
        }
#pragma unroll
        for (int q = 0; q < NX; ++q) {
            int i = tid + q * 256;
            int r = i / (BK / 4), cc = i % (BK / 4);
            *(float4*)&Xs[b][r * XP + cc * 4] = xreg[q];
        }
    };

    float acc[4][8] = {};

    loadRegs(0);
    writeLDS(0);
    __syncthreads();

    for (int c = 0; c < NCH; ++c) {
        const int b = c & 1;
        if (c + 1 < NCH) loadRegs((c + 1) * BK);
#pragma unroll
        for (int kk = 0; kk < BK; kk += 4) {
            float4 xv[4];
#pragma unroll
            for (int r = 0; r < 4; ++r)
                xv[r] = *(const float4*)&Xs[b][(r0 + r) * XP + kk];
#pragma unroll
            for (int j = 0; j < 4; ++j) {
                float4 w0 = *(const float4*)&Ws[b][(kk + j) * WP + c0g];
                float4 w1 = *(const float4*)&Ws[b][(kk + j) * WP + c0g + 4];
#pragma unroll
                for (int r = 0; r < 4; ++r) {
                    float a = ((const float*)&xv[r])[j];
                    acc[r][0] = fmaf(a, w0.x, acc[r][0]);
                    acc[r][1] = fmaf(a, w0.y, acc[r][1]);
                    acc[r][2] = fmaf(a, w0.z, acc[r][2]);
                    acc[r][3] = fmaf(a, w0.w, acc[r][3]);
                    acc[r][4] = fmaf(a, w1.x, acc[r][4]);
                    acc[r][5] = fmaf(a, w1.y, acc[r][5]);
                    acc[r][6] = fmaf(a, w1.z, acc[r][6]);
                    acc[r][7] = fmaf(a, w1.w, acc[r][7]);
                }
            }
        }
        if (c + 1 < NCH) {
            writeLDS(b ^ 1);
            __syncthreads();
        }
    }

#pragma unroll
    for (int r = 0; r < 4; ++r) {
        int gr = row0 + r0 + r;
        if (gr < n) {
            float s = dinv[gr];
            ushort8 o;
#pragma unroll
            for (int j = 0; j < 8; ++j) o[j] = f2bf(acc[r][j] * s);
            *(ushort8*)(G + (size_t)gr * COUT + c0) = o;
        }
    }
}

// ---------- pull-reduce (bf16 gathers, fp32 accumulate, 8-deep unroll) ----------

template <bool RELU>
__global__ __launch_bounds__(256) void k_reduce128(const int* __restrict__ offs,
                                                   const int* __restrict__ srt,
                                                   const unsigned* __restrict__ g,  // [n][64] dwords
                                                   const float* __restrict__ dinv,
                                                   const float* __restrict__ bias,
                                                   float* __restrict__ out, int n) {
    int node = blockIdx.x * 4 + (threadIdx.x >> 6);
    if (node >= n) return;
    int lane = threadIdx.x & 63;
    int beg = offs[node], end = offs[node + 1];

    unsigned su = g[(size_t)node * 64 + lane];  // self-loop term
    float2 a0 = make_float2(bflo(su), bfhi(su));
    float2 a1 = make_float2(0.f, 0.f);
    int j = beg;
    for (; j + 7 < end; j += 8) {
        unsigned u[8];
#pragma unroll
        for (int i = 0; i < 8; ++i) u[i] = g[(size_t)srt[j + i] * 64 + lane];
#pragma unroll
        for (int i = 0; i < 8; i += 2) {
            a0.x += bflo(u[i]);     a0.y += bfhi(u[i]);
            a1.x += bflo(u[i + 1]); a1.y += bfhi(u[i + 1]);
        }
    }
    for (; j + 1 < end; j += 2) {
        unsigned u0 = g[(size_t)srt[j] * 64 + lane];
        unsigned u1 = g[(size_t)srt[j + 1] * 64 + lane];
        a0.x += bflo(u0); a0.y += bfhi(u0);
        a1.x += bflo(u1); a1.y += bfhi(u1);
    }
    if (j < end) {
        unsigned u = g[(size_t)srt[j] * 64 + lane];
        a0.x += bflo(u); a0.y += bfhi(u);
    }
    float di = dinv[node];
    float2 b = ((const float2*)bias)[lane];
    float2 o;
    o.x = fmaf(di, a0.x + a1.x, b.x);
    o.y = fmaf(di, a0.y + a1.y, b.y);
    if (RELU) { o.x = fmaxf(o.x, 0.f); o.y = fmaxf(o.y, 0.f); }
    ((float2*)out)[(size_t)node * 64 + lane] = o;
}

template <bool RELU>
__global__ __launch_bounds__(256) void k_reduce64(const int* __restrict__ offs,
                                                  const int* __restrict__ srt,
                                                  const unsigned* __restrict__ g,  // [n][32] dwords
                                                  const float* __restrict__ dinv,
                                                  const float* __restrict__ bias,
                                                  float* __restrict__ out, int n) {
    int node = blockIdx.x * 4 + (threadIdx.x >> 6);
    if (node >= n) return;
    int lane = threadIdx.x & 63;
    int half = lane >> 5, l31 = lane & 31;
    int beg = offs[node], end = offs[node + 1];

    float2 aA = make_float2(0.f, 0.f), aB = make_float2(0.f, 0.f);
    if (half == 0) {  // self-loop term
        unsigned u = g[(size_t)node * 32 + l31];
        aA.x += bflo(u); aA.y += bfhi(u);
    }
    int j = beg;
    for (; j + 7 < end; j += 8) {
        unsigned u[4];
#pragma unroll
        for (int i = 0; i < 4; ++i) u[i] = g[(size_t)srt[j + 2 * i + half] * 32 + l31];
#pragma unroll
        for (int i = 0; i < 4; i += 2) {
            aA.x += bflo(u[i]);     aA.y += bfhi(u[i]);
            aB.x += bflo(u[i + 1]); aB.y += bfhi(u[i + 1]);
        }
    }
    for (; j + 3 < end; j += 4) {
        unsigned uA = g[(size_t)srt[j + half] * 32 + l31];
        unsigned uB = g[(size_t)srt[j + 2 + half] * 32 + l31];
        aA.x += bflo(uA); aA.y += bfhi(uA);
        aB.x += bflo(uB); aB.y += bfhi(uB);
    }
    for (; j + 1 < end; j += 2) {
        unsigned u = g[(size_t)srt[j + half] * 32 + l31];
        aA.x += bflo(u); aA.y += bfhi(u);
    }
    if (j < end && half == 0) {
        unsigned u = g[(size_t)srt[j] * 32 + l31];
        aA.x += bflo(u); aA.y += bfhi(u);
    }
    float2 a = make_float2(aA.x + aB.x, aA.y + aB.y);
    a.x += __shfl_xor(a.x, 32);
    a.y += __shfl_xor(a.y, 32);
    if (half == 0) {
        float di = dinv[node];
        float2 b = ((const float2*)bias)[l31];
        float2 o;
        o.x = fmaf(di, a.x, b.x);
        o.y = fmaf(di, a.y, b.y);
        if (RELU) { o.x = fmaxf(o.x, 0.f); o.y = fmaxf(o.y, 0.f); }
        ((float2*)out)[(size_t)node * 32 + l31] = o;
    }
}

extern "C" void kernel_launch(void* const* d_in, const int* in_sizes, int n_in,
                              void* d_out, int out_size, void* d_ws, size_t ws_size,
                              hipStream_t stream) {
    const float* x  = (const float*)d_in[0];
    const int*   ei = (const int*)d_in[1];   // [2, E] int32
    const float* W1 = (const float*)d_in[2];
    const float* b1 = (const float*)d_in[3];
    const float* W2 = (const float*)d_in[4];
    const float* b2 = (const float*)d_in[5];
    float* out = (float*)d_out;

    const int n = in_sizes[0] / K;   // 50000
    const int e = in_sizes[1] / 2;   // 800000
    const int nb = (n + 255) / 256;  // 196 buckets

    // workspace layout (8B-aligned head first)
    char* p = (char*)d_ws;
    unsigned long long* tmp = (unsigned long long*)p;  p += (size_t)e * 8;  // (dst,src) pairs
    int* bcnt  = (int*)p;  p += 256 * 4;
    int* bbase = (int*)p;  p += 257 * 4;
    int* gcur  = (int*)p;  p += 256 * 4;
    int* offs  = (int*)p;  p += (size_t)(n + 1) * 4;
    int* srt   = (int*)p;  p += (size_t)e * 4;
    float* dinv = (float*)p;  p += (size_t)n * 4;
    p = (char*)(((uintptr_t)p + 15) & ~(uintptr_t)15);
    unsigned short* G1 = (unsigned short*)p;  p += (size_t)n * 128 * 2;  // bf16 [n][128]
    p = (char*)(((uintptr_t)p + 15) & ~(uintptr_t)15);
    float* H = (float*)p;  p += (size_t)n * 128 * 4;                     // fp32 [n][128]
    p = (char*)(((uintptr_t)p + 15) & ~(uintptr_t)15);
    unsigned short* G2 = (unsigned short*)p;                             // bf16 [n][64]

    // CSR build
    k_zerob<<<1, 256, 0, stream>>>(bcnt);
    k_bcount<<<512, 256, 0, stream>>>(ei + e, e, bcnt, nb);
    k_bscan<<<1, 256, 0, stream>>>(bcnt, bbase, gcur, nb, offs, n, e);
    k_bin<<<(e + 2047) / 2048, 256, 0, stream>>>(ei, e, gcur, tmp);
    k_csr<<<nb, 256, 0, stream>>>(tmp, bbase, offs, srt, dinv, n);

    // Layer 1: H = relu(dinv ⊙ (A_hat G1) + b1), G1 = dinv ⊙ (x@W1)
    k_gemm_scale<128><<<(n + 63) / 64, 256, 0, stream>>>(x, W1, dinv, G1, n);
    k_reduce128<true><<<(n + 3) / 4, 256, 0, stream>>>(offs, srt, (const unsigned*)G1,
                                                       dinv, b1, H, n);

    // Layer 2: out = dinv ⊙ (A_hat G2) + b2, G2 = dinv ⊙ (H@W2)
    k_gemm_scale<64><<<(n + 127) / 128, 256, 0, stream>>>(H, W2, dinv, G2, n);
    k_reduce64<false><<<(n + 3) / 4, 256, 0, stream>>>(offs, srt, (const unsigned*)G2,
                                                       dinv, b2, out, n);
}

// Round 7
// 159.555 us; speedup vs baseline: 13.1825x; 1.1004x over previous
//
#include <hip/hip_runtime.h>

static constexpr int K = 128;  // inner dim of both layers (in_ch = hid = 128)

using ushort8 = __attribute__((ext_vector_type(8))) unsigned short;
using bf16x8  = __attribute__((ext_vector_type(8))) __bf16;
using f32x4   = __attribute__((ext_vector_type(4))) float;

__device__ inline float bflo(unsigned u) { return __uint_as_float(u << 16); }
__device__ inline float bfhi(unsigned u) { return __uint_as_float(u & 0xFFFF0000u); }
__device__ inline unsigned short f2bf(float f) {  // round-to-nearest-even
    unsigned u = __float_as_uint(f);
    return (unsigned short)((u + 0x7FFF + ((u >> 16) & 1)) >> 16);
}

// ---------- CSR build via 2-level binned counting sort ----------
// bucket c = dst >> 8 (256 nodes per bucket); bucket regions ARE the final CSR regions.

__global__ __launch_bounds__(256) void k_zerob(int* __restrict__ bcnt) {
    bcnt[threadIdx.x] = 0;
}

__global__ __launch_bounds__(256) void k_bcount(const int* __restrict__ dst, int e,
                                                int* __restrict__ bcnt, int nb) {
    __shared__ int c[256];
    int t = threadIdx.x;
    c[t] = 0;
    __syncthreads();
    for (int i = blockIdx.x * 256 + t; i < e; i += gridDim.x * 256)
        atomicAdd(&c[dst[i] >> 8], 1);
    __syncthreads();
    if (t < nb && c[t]) atomicAdd(&bcnt[t], c[t]);
}

__global__ __launch_bounds__(256) void k_bscan(const int* __restrict__ bcnt,
                                               int* __restrict__ bbase,
                                               int* __restrict__ gcur,
                                               int nb, int* __restrict__ offs,
                                               int n, int e) {
    __shared__ int sh[256];
    int t = threadIdx.x;
    int v = (t < nb) ? bcnt[t] : 0;
    sh[t] = v;
    __syncthreads();
    for (int o = 1; o < 256; o <<= 1) {
        int x = (t >= o) ? sh[t - o] : 0;
        __syncthreads();
        sh[t] += x;
        __syncthreads();
    }
    int excl = sh[t] - v;
    bbase[t] = excl;
    gcur[t] = excl;
    if (t == 255) bbase[256] = sh[255];
    if (t == 0) offs[n] = e;
}

__global__ __launch_bounds__(256) void k_bin(const int* __restrict__ ei, int e,
                                             int* __restrict__ gcur,
                                             unsigned long long* __restrict__ tmp) {
    constexpr int PER = 8;
    __shared__ int cnt[256], base[256], cur[256];
    int t = threadIdx.x;
    int chunk0 = blockIdx.x * 256 * PER;
    cnt[t] = 0;
    __syncthreads();
    int ds[PER];
#pragma unroll
    for (int k2 = 0; k2 < PER; ++k2) {
        int i = chunk0 + k2 * 256 + t;
        ds[k2] = (i < e) ? ei[(size_t)e + i] : -1;
        if (ds[k2] >= 0) atomicAdd(&cnt[ds[k2] >> 8], 1);
    }
    __syncthreads();
    int c = cnt[t];
    base[t] = c ? atomicAdd(&gcur[t], c) : 0;
    cur[t] = 0;
    __syncthreads();
#pragma unroll
    for (int k2 = 0; k2 < PER; ++k2) {
        int i = chunk0 + k2 * 256 + t;
        if (i < e) {
            int b = ds[k2] >> 8;
            int pos = base[b] + atomicAdd(&cur[b], 1);
            tmp[pos] = ((unsigned long long)(unsigned)ds[k2] << 32) | (unsigned)ei[i];
        }
    }
}

__global__ __launch_bounds__(256) void k_csr(const unsigned long long* __restrict__ tmp,
                                             const int* __restrict__ bbase,
                                             int* __restrict__ offs,
                                             int* __restrict__ srt,
                                             float* __restrict__ dinv, int n) {
    __shared__ int cntS[256], sh[256], cur[256];
    int b = blockIdx.x;
    int t = threadIdx.x;
    int beg = bbase[b], end = bbase[b + 1];
    cntS[t] = 0;
    __syncthreads();
    for (int i = beg + t; i < end; i += 256)
        atomicAdd(&cntS[(int)(tmp[i] >> 32) & 255], 1);
    __syncthreads();
    int v = cntS[t];
    sh[t] = v;
    __syncthreads();
    for (int o = 1; o < 256; o <<= 1) {
        int x = (t >= o) ? sh[t - o] : 0;
        __syncthreads();
        sh[t] += x;
        __syncthreads();
    }
    int pfx = sh[t] - v;
    int node = b * 256 + t;
    if (node < n) {
        offs[node] = beg + pfx;
        dinv[node] = rsqrtf((float)(v + 1));  // deg incl. self-loop
    }
    cur[t] = pfx;
    __syncthreads();
    for (int i = beg + t; i < end; i += 256) {
        unsigned long long pr = tmp[i];
        int d = (int)(pr >> 32);
        int pos = atomicAdd(&cur[d & 255], 1);
        srt[beg + pos] = (int)(pr & 0xFFFFFFFFu);
    }
}

// ---------- G(bf16) = dinv ⊙ (X @ W); MFMA split-bf16 (hi/lo) GEMM ----------
// fp32 ≈ hi(bf16) + lo(bf16); X@W = Ah·Bh + Al·Bh + Ah·Bl (fp32 MFMA accum).
// Tile: 64 rows × COUT, BK=32 (one 16x16x32 MFMA K-step), 4 waves × 16-row slab.
// LDS layout k-contiguous, 64 B row stride -> dense 1024 B fragment windows
// (conflict-free ds_read_b128). W staged transposed (col-major) for B-frags.

template <int COUT>
__global__ __launch_bounds__(256) void k_gemm_mfma(const float* __restrict__ X,
                                                   const float* __restrict__ W,
                                                   const float* __restrict__ dinv,
                                                   unsigned short* __restrict__ G, int n) {
    constexpr int BM = 64, BK = 32;
    constexpr int NCT = COUT / 16;            // col tiles per wave: 8 | 4
    constexpr int NCH = K / BK;               // 4 K-chunks
    constexpr int WT = COUT * (BK / 8) / 256; // W tasks/thread: 2 | 1
    __shared__ unsigned short Ah[BM * BK], Al[BM * BK];
    __shared__ unsigned short Bh[COUT * BK], Bl[COUT * BK];
    __shared__ float dS[BM];
    const int tid = threadIdx.x;
    const int row0 = blockIdx.x * BM;
    if (tid < BM) {
        int gr = row0 + tid;
        dS[tid] = (gr < n) ? dinv[gr] : 0.f;
    }

    float4 xr[2];      // X prefetch: 1 task (r, ks): 8 floats
    float wr[WT][8];   // W prefetch

    auto loadX = [&](int kc) {
        int r = tid >> 2, ks = tid & 3;
        int gr = row0 + r;
        if (gr < n) {
            const float4* pp = (const float4*)(X + (size_t)gr * K + kc * BK + ks * 8);
            xr[0] = pp[0];
            xr[1] = pp[1];
        } else {
            xr[0] = make_float4(0.f, 0.f, 0.f, 0.f);
            xr[1] = xr[0];
        }
    };
    auto loadW = [&](int kc) {
#pragma unroll
        for (int q = 0; q < WT; ++q) {
            int i = tid + q * 256;
            int c = i % COUT, ks = i / COUT;
#pragma unroll
            for (int j = 0; j < 8; ++j)
                wr[q][j] = W[(size_t)(kc * BK + ks * 8 + j) * COUT + c];
        }
    };
    auto storeLDS = [&]() {
        int r = tid >> 2, ks = tid & 3;
        ushort8 h, l;
        const float* f = (const float*)&xr[0];
#pragma unroll
        for (int j = 0; j < 8; ++j) {
            unsigned short hh = f2bf(f[j]);
            h[j] = hh;
            l[j] = f2bf(f[j] - __uint_as_float((unsigned)hh << 16));
        }
        *(ushort8*)&Ah[r * BK + ks * 8] = h;
        *(ushort8*)&Al[r * BK + ks * 8] = l;
#pragma unroll
        for (int q = 0; q < WT; ++q) {
            int i = tid + q * 256;
            int c = i % COUT, ks2 = i / COUT;
            ushort8 wh, wl;
#pragma unroll
            for (int j = 0; j < 8; ++j) {
                unsigned short hh = f2bf(wr[q][j]);
                wh[j] = hh;
                wl[j] = f2bf(wr[q][j] - __uint_as_float((unsigned)hh << 16));
            }
            *(ushort8*)&Bh[c * BK + ks2 * 8] = wh;
            *(ushort8*)&Bl[c * BK + ks2 * 8] = wl;
        }
    };

    f32x4 acc[NCT] = {};
    const int l = tid & 63, wv = tid >> 6;
    const int l16 = l & 15, lk = l >> 4;
    const int arow = wv * 16 + l16;

    loadX(0);
    loadW(0);
    storeLDS();
    __syncthreads();
    for (int c = 0; c < NCH; ++c) {
        if (c + 1 < NCH) { loadX(c + 1); loadW(c + 1); }
        bf16x8 ah = *(const bf16x8*)&Ah[arow * BK + lk * 8];
        bf16x8 al = *(const bf16x8*)&Al[arow * BK + lk * 8];
#pragma unroll
        for (int ct = 0; ct < NCT; ++ct) {
            bf16x8 bh = *(const bf16x8*)&Bh[(ct * 16 + l16) * BK + lk * 8];
            bf16x8 bl = *(const bf16x8*)&Bl[(ct * 16 + l16) * BK + lk * 8];
            acc[ct] = __builtin_amdgcn_mfma_f32_16x16x32_bf16(ah, bh, acc[ct], 0, 0, 0);
            acc[ct] = __builtin_amdgcn_mfma_f32_16x16x32_bf16(al, bh, acc[ct], 0, 0, 0);
            acc[ct] = __builtin_amdgcn_mfma_f32_16x16x32_bf16(ah, bl, acc[ct], 0, 0, 0);
        }
        if (c + 1 < NCH) {
            __syncthreads();
            storeLDS();
            __syncthreads();
        }
    }

    // epilogue: C/D mapping col = lane&15, row = (lane>>4)*4 + reg  [m89-verified]
#pragma unroll
    for (int ct = 0; ct < NCT; ++ct) {
        int col = ct * 16 + l16;
#pragma unroll
        for (int r4 = 0; r4 < 4; ++r4) {
            int lr = wv * 16 + lk * 4 + r4;
            int gr = row0 + lr;
            if (gr < n) G[(size_t)gr * COUT + col] = f2bf(acc[ct][r4] * dS[lr]);
        }
    }
}

// ---------- pull-reduce (bf16 gathers, fp32 accumulate, 8-deep unroll) ----------

template <bool RELU>
__global__ __launch_bounds__(256) void k_reduce128(const int* __restrict__ offs,
                                                   const int* __restrict__ srt,
                                                   const unsigned* __restrict__ g,  // [n][64] dwords
                                                   const float* __restrict__ dinv,
                                                   const float* __restrict__ bias,
                                                   float* __restrict__ out, int n) {
    int node = blockIdx.x * 4 + (threadIdx.x >> 6);
    if (node >= n) return;
    int lane = threadIdx.x & 63;
    int beg = offs[node], end = offs[node + 1];

    unsigned su = g[(size_t)node * 64 + lane];  // self-loop term
    float2 a0 = make_float2(bflo(su), bfhi(su));
    float2 a1 = make_float2(0.f, 0.f);
    int j = beg;
    for (; j + 7 < end; j += 8) {
        unsigned u[8];
#pragma unroll
        for (int i = 0; i < 8; ++i) u[i] = g[(size_t)srt[j + i] * 64 + lane];
#pragma unroll
        for (int i = 0; i < 8; i += 2) {
            a0.x += bflo(u[i]);     a0.y += bfhi(u[i]);
            a1.x += bflo(u[i + 1]); a1.y += bfhi(u[i + 1]);
        }
    }
    for (; j + 1 < end; j += 2) {
        unsigned u0 = g[(size_t)srt[j] * 64 + lane];
        unsigned u1 = g[(size_t)srt[j + 1] * 64 + lane];
        a0.x += bflo(u0); a0.y += bfhi(u0);
        a1.x += bflo(u1); a1.y += bfhi(u1);
    }
    if (j < end) {
        unsigned u = g[(size_t)srt[j] * 64 + lane];
        a0.x += bflo(u); a0.y += bfhi(u);
    }
    float di = dinv[node];
    float2 b = ((const float2*)bias)[lane];
    float2 o;
    o.x = fmaf(di, a0.x + a1.x, b.x);
    o.y = fmaf(di, a0.y + a1.y, b.y);
    if (RELU) { o.x = fmaxf(o.x, 0.f); o.y = fmaxf(o.y, 0.f); }
    ((float2*)out)[(size_t)node * 64 + lane] = o;
}

template <bool RELU>
__global__ __launch_bounds__(256) void k_reduce64(const int* __restrict__ offs,
                                                  const int* __restrict__ srt,
                                                  const unsigned* __restrict__ g,  // [n][32] dwords
                                                  const float* __restrict__ dinv,
                                                  const float* __restrict__ bias,
                                                  float* __restrict__ out, int n) {
    int node = blockIdx.x * 4 + (threadIdx.x >> 6);
    if (node >= n) return;
    int lane = threadIdx.x & 63;
    int half = lane >> 5, l31 = lane & 31;
    int beg = offs[node], end = offs[node + 1];

    float2 aA = make_float2(0.f, 0.f), aB = make_float2(0.f, 0.f);
    if (half == 0) {  // self-loop term
        unsigned u = g[(size_t)node * 32 + l31];
        aA.x += bflo(u); aA.y += bfhi(u);
    }
    int j = beg;
    for (; j + 7 < end; j += 8) {
        unsigned u[4];
#pragma unroll
        for (int i = 0; i < 4; ++i) u[i] = g[(size_t)srt[j + 2 * i + half] * 32 + l31];
#pragma unroll
        for (int i = 0; i < 4; i += 2) {
            aA.x += bflo(u[i]);     aA.y += bfhi(u[i]);
            aB.x += bflo(u[i + 1]); aB.y += bfhi(u[i + 1]);
        }
    }
    for (; j + 3 < end; j += 4) {
        unsigned uA = g[(size_t)srt[j + half] * 32 + l31];
        unsigned uB = g[(size_t)srt[j + 2 + half] * 32 + l31];
        aA.x += bflo(uA); aA.y += bfhi(uA);
        aB.x += bflo(uB); aB.y += bfhi(uB);
    }
    for (; j + 1 < end; j += 2) {
        unsigned u = g[(size_t)srt[j + half] * 32 + l31];
        aA.x += bflo(u); aA.y += bfhi(u);
    }
    if (j < end && half == 0) {
        unsigned u = g[(size_t)srt[j] * 32 + l31];
        aA.x += bflo(u); aA.y += bfhi(u);
    }
    float2 a = make_float2(aA.x + aB.x, aA.y + aB.y);
    a.x += __shfl_xor(a.x, 32);
    a.y += __shfl_xor(a.y, 32);
    if (half == 0) {
        float di = dinv[node];
        float2 b = ((const float2*)bias)[l31];
        float2 o;
        o.x = fmaf(di, a.x, b.x);
        o.y = fmaf(di, a.y, b.y);
        if (RELU) { o.x = fmaxf(o.x, 0.f); o.y = fmaxf(o.y, 0.f); }
        ((float2*)out)[(size_t)node * 32 + l31] = o;
    }
}

extern "C" void kernel_launch(void* const* d_in, const int* in_sizes, int n_in,
                              void* d_out, int out_size, void* d_ws, size_t ws_size,
                              hipStream_t stream) {
    const float* x  = (const float*)d_in[0];
    const int*   ei = (const int*)d_in[1];   // [2, E] int32
    const float* W1 = (const float*)d_in[2];
    const float* b1 = (const float*)d_in[3];
    const float* W2 = (const float*)d_in[4];
    const float* b2 = (const float*)d_in[5];
    float* out = (float*)d_out;

    const int n = in_sizes[0] / K;   // 50000
    const int e = in_sizes[1] / 2;   // 800000
    const int nb = (n + 255) / 256;  // 196 buckets

    // workspace layout (8B-aligned head first)
    char* p = (char*)d_ws;
    unsigned long long* tmp = (unsigned long long*)p;  p += (size_t)e * 8;  // (dst,src) pairs
    int* bcnt  = (int*)p;  p += 256 * 4;
    int* bbase = (int*)p;  p += 257 * 4;
    int* gcur  = (int*)p;  p += 256 * 4;
    int* offs  = (int*)p;  p += (size_t)(n + 1) * 4;
    int* srt   = (int*)p;  p += (size_t)e * 4;
    float* dinv = (float*)p;  p += (size_t)n * 4;
    p = (char*)(((uintptr_t)p + 15) & ~(uintptr_t)15);
    unsigned short* G1 = (unsigned short*)p;  p += (size_t)n * 128 * 2;  // bf16 [n][128]
    p = (char*)(((uintptr_t)p + 15) & ~(uintptr_t)15);
    float* H = (float*)p;  p += (size_t)n * 128 * 4;                     // fp32 [n][128]
    p = (char*)(((uintptr_t)p + 15) & ~(uintptr_t)15);
    unsigned short* G2 = (unsigned short*)p;                             // bf16 [n][64]

    // CSR build
    k_zerob<<<1, 256, 0, stream>>>(bcnt);
    k_bcount<<<512, 256, 0, stream>>>(ei + e, e, bcnt, nb);
    k_bscan<<<1, 256, 0, stream>>>(bcnt, bbase, gcur, nb, offs, n, e);
    k_bin<<<(e + 2047) / 2048, 256, 0, stream>>>(ei, e, gcur, tmp);
    k_csr<<<nb, 256, 0, stream>>>(tmp, bbase, offs, srt, dinv, n);

    // Layer 1: H = relu(dinv ⊙ (A_hat G1) + b1), G1 = dinv ⊙ (x@W1)
    k_gemm_mfma<128><<<(n + 63) / 64, 256, 0, stream>>>(x, W1, dinv, G1, n);
    k_reduce128<true><<<(n + 3) / 4, 256, 0, stream>>>(offs, srt, (const unsigned*)G1,
                                                       dinv, b1, H, n);

    // Layer 2: out = dinv ⊙ (A_hat G2) + b2, G2 = dinv ⊙ (H@W2)
    k_gemm_mfma<64><<<(n + 63) / 64, 256, 0, stream>>>(H, W2, dinv, G2, n);
    k_reduce64<false><<<(n + 3) / 4, 256, 0, stream>>>(offs, srt, (const unsigned*)G2,
                                                       dinv, b2, out, n);
}

// Round 8
// 156.048 us; speedup vs baseline: 13.4788x; 1.0225x over previous
//
#include <hip/hip_runtime.h>

static constexpr int K = 128;  // inner dim of both layers (in_ch = hid = 128)

using ushort8 = __attribute__((ext_vector_type(8))) unsigned short;
using bf16x8  = __attribute__((ext_vector_type(8))) __bf16;
using f32x4   = __attribute__((ext_vector_type(4))) float;

__device__ inline float bflo(unsigned u) { return __uint_as_float(u << 16); }
__device__ inline float bfhi(unsigned u) { return __uint_as_float(u & 0xFFFF0000u); }
__device__ inline unsigned short f2bf(float f) {  // round-to-nearest-even
    unsigned u = __float_as_uint(f);
    return (unsigned short)((u + 0x7FFF + ((u >> 16) & 1)) >> 16);
}

// ---------- CSR build via 2-level binned counting sort ----------

__global__ __launch_bounds__(256) void k_zerob(int* __restrict__ bcnt) {
    bcnt[threadIdx.x] = 0;
}

__global__ __launch_bounds__(256) void k_bcount(const int* __restrict__ dst, int e,
                                                int* __restrict__ bcnt, int nb) {
    __shared__ int c[256];
    int t = threadIdx.x;
    c[t] = 0;
    __syncthreads();
    for (int i = blockIdx.x * 256 + t; i < e; i += gridDim.x * 256)
        atomicAdd(&c[dst[i] >> 8], 1);
    __syncthreads();
    if (t < nb && c[t]) atomicAdd(&bcnt[t], c[t]);
}

__global__ __launch_bounds__(256) void k_bscan(const int* __restrict__ bcnt,
                                               int* __restrict__ bbase,
                                               int* __restrict__ gcur,
                                               int nb, int* __restrict__ offs,
                                               int n, int e) {
    __shared__ int sh[256];
    int t = threadIdx.x;
    int v = (t < nb) ? bcnt[t] : 0;
    sh[t] = v;
    __syncthreads();
    for (int o = 1; o < 256; o <<= 1) {
        int x = (t >= o) ? sh[t - o] : 0;
        __syncthreads();
        sh[t] += x;
        __syncthreads();
    }
    int excl = sh[t] - v;
    bbase[t] = excl;
    gcur[t] = excl;
    if (t == 255) bbase[256] = sh[255];
    if (t == 0) offs[n] = e;
}

__global__ __launch_bounds__(256) void k_bin(const int* __restrict__ ei, int e,
                                             int* __restrict__ gcur,
                                             unsigned long long* __restrict__ tmp) {
    constexpr int PER = 8;
    __shared__ int cnt[256], base[256], cur[256];
    int t = threadIdx.x;
    int chunk0 = blockIdx.x * 256 * PER;
    cnt[t] = 0;
    __syncthreads();
    int ds[PER];
#pragma unroll
    for (int k2 = 0; k2 < PER; ++k2) {
        int i = chunk0 + k2 * 256 + t;
        ds[k2] = (i < e) ? ei[(size_t)e + i] : -1;
        if (ds[k2] >= 0) atomicAdd(&cnt[ds[k2] >> 8], 1);
    }
    __syncthreads();
    int c = cnt[t];
    base[t] = c ? atomicAdd(&gcur[t], c) : 0;
    cur[t] = 0;
    __syncthreads();
#pragma unroll
    for (int k2 = 0; k2 < PER; ++k2) {
        int i = chunk0 + k2 * 256 + t;
        if (i < e) {
            int b = ds[k2] >> 8;
            int pos = base[b] + atomicAdd(&cur[b], 1);
            tmp[pos] = ((unsigned long long)(unsigned)ds[k2] << 32) | (unsigned)ei[i];
        }
    }
}

__global__ __launch_bounds__(256) void k_csr(const unsigned long long* __restrict__ tmp,
                                             const int* __restrict__ bbase,
                                             int* __restrict__ offs,
                                             int* __restrict__ srt,
                                             float* __restrict__ dinv, int n) {
    __shared__ int cntS[256], sh[256], cur[256];
    int b = blockIdx.x;
    int t = threadIdx.x;
    int beg = bbase[b], end = bbase[b + 1];
    cntS[t] = 0;
    __syncthreads();
    for (int i = beg + t; i < end; i += 256)
        atomicAdd(&cntS[(int)(tmp[i] >> 32) & 255], 1);
    __syncthreads();
    int v = cntS[t];
    sh[t] = v;
    __syncthreads();
    for (int o = 1; o < 256; o <<= 1) {
        int x = (t >= o) ? sh[t - o] : 0;
        __syncthreads();
        sh[t] += x;
        __syncthreads();
    }
    int pfx = sh[t] - v;
    int node = b * 256 + t;
    if (node < n) {
        offs[node] = beg + pfx;
        dinv[node] = rsqrtf((float)(v + 1));  // deg incl. self-loop
    }
    cur[t] = pfx;
    __syncthreads();
    for (int i = beg + t; i < end; i += 256) {
        unsigned long long pr = tmp[i];
        int d = (int)(pr >> 32);
        int pos = atomicAdd(&cur[d & 255], 1);
        srt[beg + pos] = (int)(pr & 0xFFFFFFFFu);
    }
}

// ---------- G(bf16) = dinv ⊙ (X @ W); MFMA split-bf16 (hi/lo) GEMM ----------

template <int COUT>
__global__ __launch_bounds__(256) void k_gemm_mfma(const float* __restrict__ X,
                                                   const float* __restrict__ W,
                                                   const float* __restrict__ dinv,
                                                   unsigned short* __restrict__ G, int n) {
    constexpr int BM = 64, BK = 32;
    constexpr int NCT = COUT / 16;            // col tiles per wave: 8 | 4
    constexpr int NCH = K / BK;               // 4 K-chunks
    constexpr int WT = COUT * (BK / 8) / 256; // W tasks/thread: 2 | 1
    __shared__ unsigned short Ah[BM * BK], Al[BM * BK];
    __shared__ unsigned short Bh[COUT * BK], Bl[COUT * BK];
    __shared__ float dS[BM];
    const int tid = threadIdx.x;
    const int row0 = blockIdx.x * BM;
    if (tid < BM) {
        int gr = row0 + tid;
        dS[tid] = (gr < n) ? dinv[gr] : 0.f;
    }

    float4 xr[2];
    float wr[WT][8];

    auto loadX = [&](int kc) {
        int r = tid >> 2, ks = tid & 3;
        int gr = row0 + r;
        if (gr < n) {
            const float4* pp = (const float4*)(X + (size_t)gr * K + kc * BK + ks * 8);
            xr[0] = pp[0];
            xr[1] = pp[1];
        } else {
            xr[0] = make_float4(0.f, 0.f, 0.f, 0.f);
            xr[1] = xr[0];
        }
    };
    auto loadW = [&](int kc) {
#pragma unroll
        for (int q = 0; q < WT; ++q) {
            int i = tid + q * 256;
            int c = i % COUT, ks = i / COUT;
#pragma unroll
            for (int j = 0; j < 8; ++j)
                wr[q][j] = W[(size_t)(kc * BK + ks * 8 + j) * COUT + c];
        }
    };
    auto storeLDS = [&]() {
        int r = tid >> 2, ks = tid & 3;
        ushort8 h, l;
        const float* f = (const float*)&xr[0];
#pragma unroll
        for (int j = 0; j < 8; ++j) {
            unsigned short hh = f2bf(f[j]);
            h[j] = hh;
            l[j] = f2bf(f[j] - __uint_as_float((unsigned)hh << 16));
        }
        *(ushort8*)&Ah[r * BK + ks * 8] = h;
        *(ushort8*)&Al[r * BK + ks * 8] = l;
#pragma unroll
        for (int q = 0; q < WT; ++q) {
            int i = tid + q * 256;
            int c = i % COUT, ks2 = i / COUT;
            ushort8 wh, wl;
#pragma unroll
            for (int j = 0; j < 8; ++j) {
                unsigned short hh = f2bf(wr[q][j]);
                wh[j] = hh;
                wl[j] = f2bf(wr[q][j] - __uint_as_float((unsigned)hh << 16));
            }
            *(ushort8*)&Bh[c * BK + ks2 * 8] = wh;
            *(ushort8*)&Bl[c * BK + ks2 * 8] = wl;
        }
    };

    f32x4 acc[NCT] = {};
    const int l = tid & 63, wv = tid >> 6;
    const int l16 = l & 15, lk = l >> 4;
    const int arow = wv * 16 + l16;

    loadX(0);
    loadW(0);
    storeLDS();
    __syncthreads();
    for (int c = 0; c < NCH; ++c) {
        if (c + 1 < NCH) { loadX(c + 1); loadW(c + 1); }
        bf16x8 ah = *(const bf16x8*)&Ah[arow * BK + lk * 8];
        bf16x8 al = *(const bf16x8*)&Al[arow * BK + lk * 8];
#pragma unroll
        for (int ct = 0; ct < NCT; ++ct) {
            bf16x8 bh = *(const bf16x8*)&Bh[(ct * 16 + l16) * BK + lk * 8];
            bf16x8 bl = *(const bf16x8*)&Bl[(ct * 16 + l16) * BK + lk * 8];
            acc[ct] = __builtin_amdgcn_mfma_f32_16x16x32_bf16(ah, bh, acc[ct], 0, 0, 0);
            acc[ct] = __builtin_amdgcn_mfma_f32_16x16x32_bf16(al, bh, acc[ct], 0, 0, 0);
            acc[ct] = __builtin_amdgcn_mfma_f32_16x16x32_bf16(ah, bl, acc[ct], 0, 0, 0);
        }
        if (c + 1 < NCH) {
            __syncthreads();
            storeLDS();
            __syncthreads();
        }
    }

#pragma unroll
    for (int ct = 0; ct < NCT; ++ct) {
        int col = ct * 16 + l16;
#pragma unroll
        for (int r4 = 0; r4 < 4; ++r4) {
            int lr = wv * 16 + lk * 4 + r4;
            int gr = row0 + lr;
            if (gr < n) G[(size_t)gr * COUT + col] = f2bf(acc[ct][r4] * dS[lr]);
        }
    }
}

// ---------- pull-reduce: 16B/lane gathers, sub-wave edge groups ----------

#define ADD8(u)                                      \
    do {                                             \
        a[0] += bflo((u).x); a[1] += bfhi((u).x);    \
        a[2] += bflo((u).y); a[3] += bfhi((u).y);    \
        a[4] += bflo((u).z); a[5] += bfhi((u).z);    \
        a[6] += bflo((u).w); a[7] += bfhi((u).w);    \
    } while (0)

// COUT=128: 4 groups x 16 lanes; each group gathers one edge row (uint4/lane).
template <bool RELU>
__global__ __launch_bounds__(256) void k_reduce128(const int* __restrict__ offs,
                                                   const int* __restrict__ srt,
                                                   const uint4* __restrict__ g4,  // [n][16]
                                                   const float* __restrict__ dinv,
                                                   const float* __restrict__ bias,
                                                   float* __restrict__ out, int n) {
    int node = blockIdx.x * 4 + (threadIdx.x >> 6);
    if (node >= n) return;
    int lane = threadIdx.x & 63;
    int l16 = lane & 15, grp = lane >> 4;
    int beg = offs[node], end = offs[node + 1];

    float a[8] = {};
    if (grp == 0) {  // self-loop term
        uint4 u = g4[(size_t)node * 16 + l16];
        ADD8(u);
    }
    int j = beg + grp;
    for (; j + 12 < end; j += 16) {  // 4 edges per group in flight
        uint4 u0 = g4[(size_t)srt[j]      * 16 + l16];
        uint4 u1 = g4[(size_t)srt[j + 4]  * 16 + l16];
        uint4 u2 = g4[(size_t)srt[j + 8]  * 16 + l16];
        uint4 u3 = g4[(size_t)srt[j + 12] * 16 + l16];
        ADD8(u0); ADD8(u1); ADD8(u2); ADD8(u3);
    }
    for (; j < end; j += 4) {
        uint4 u = g4[(size_t)srt[j] * 16 + l16];
        ADD8(u);
    }
#pragma unroll
    for (int q = 0; q < 8; ++q) {
        a[q] += __shfl_xor(a[q], 16);
        a[q] += __shfl_xor(a[q], 32);
    }
    if (lane < 16) {
        float di = dinv[node];
        float4 b0 = ((const float4*)bias)[l16 * 2];
        float4 b1 = ((const float4*)bias)[l16 * 2 + 1];
        float4 o0, o1;
        o0.x = fmaf(di, a[0], b0.x); o0.y = fmaf(di, a[1], b0.y);
        o0.z = fmaf(di, a[2], b0.z); o0.w = fmaf(di, a[3], b0.w);
        o1.x = fmaf(di, a[4], b1.x); o1.y = fmaf(di, a[5], b1.y);
        o1.z = fmaf(di, a[6], b1.z); o1.w = fmaf(di, a[7], b1.w);
        if (RELU) {
            o0.x = fmaxf(o0.x, 0.f); o0.y = fmaxf(o0.y, 0.f);
            o0.z = fmaxf(o0.z, 0.f); o0.w = fmaxf(o0.w, 0.f);
            o1.x = fmaxf(o1.x, 0.f); o1.y = fmaxf(o1.y, 0.f);
            o1.z = fmaxf(o1.z, 0.f); o1.w = fmaxf(o1.w, 0.f);
        }
        float4* op = (float4*)(out + (size_t)node * 128 + l16 * 8);
        op[0] = o0;
        op[1] = o1;
    }
}

// COUT=64: 8 groups x 8 lanes; uint4/lane covers the 128 B row.
template <bool RELU>
__global__ __launch_bounds__(256) void k_reduce64(const int* __restrict__ offs,
                                                  const int* __restrict__ srt,
                                                  const uint4* __restrict__ g4,  // [n][8]
                                                  const float* __restrict__ dinv,
                                                  const float* __restrict__ bias,
                                                  float* __restrict__ out, int n) {
    int node = blockIdx.x * 4 + (threadIdx.x >> 6);
    if (node >= n) return;
    int lane = threadIdx.x & 63;
    int l8 = lane & 7, grp = lane >> 3;
    int beg = offs[node], end = offs[node + 1];

    float a[8] = {};
    if (grp == 0) {  // self-loop term
        uint4 u = g4[(size_t)node * 8 + l8];
        ADD8(u);
    }
    int j = beg + grp;
    for (; j + 8 < end; j += 16) {  // 2 edges per group in flight
        uint4 u0 = g4[(size_t)srt[j]     * 8 + l8];
        uint4 u1 = g4[(size_t)srt[j + 8] * 8 + l8];
        ADD8(u0); ADD8(u1);
    }
    for (; j < end; j += 8) {
        uint4 u = g4[(size_t)srt[j] * 8 + l8];
        ADD8(u);
    }
#pragma unroll
    for (int q = 0; q < 8; ++q) {
        a[q] += __shfl_xor(a[q], 8);
        a[q] += __shfl_xor(a[q], 16);
        a[q] += __shfl_xor(a[q], 32);
    }
    if (lane < 8) {
        float di = dinv[node];
        float4 b0 = ((const float4*)bias)[l8 * 2];
        float4 b1 = ((const float4*)bias)[l8 * 2 + 1];
        float4 o0, o1;
        o0.x = fmaf(di, a[0], b0.x); o0.y = fmaf(di, a[1], b0.y);
        o0.z = fmaf(di, a[2], b0.z); o0.w = fmaf(di, a[3], b0.w);
        o1.x = fmaf(di, a[4], b1.x); o1.y = fmaf(di, a[5], b1.y);
        o1.z = fmaf(di, a[6], b1.z); o1.w = fmaf(di, a[7], b1.w);
        if (RELU) {
            o0.x = fmaxf(o0.x, 0.f); o0.y = fmaxf(o0.y, 0.f);
            o0.z = fmaxf(o0.z, 0.f); o0.w = fmaxf(o0.w, 0.f);
            o1.x = fmaxf(o1.x, 0.f); o1.y = fmaxf(o1.y, 0.f);
            o1.z = fmaxf(o1.z, 0.f); o1.w = fmaxf(o1.w, 0.f);
        }
        float4* op = (float4*)(out + (size_t)node * 64 + l8 * 8);
        op[0] = o0;
        op[1] = o1;
    }
}

extern "C" void kernel_launch(void* const* d_in, const int* in_sizes, int n_in,
                              void* d_out, int out_size, void* d_ws, size_t ws_size,
                              hipStream_t stream) {
    const float* x  = (const float*)d_in[0];
    const int*   ei = (const int*)d_in[1];   // [2, E] int32
    const float* W1 = (const float*)d_in[2];
    const float* b1 = (const float*)d_in[3];
    const float* W2 = (const float*)d_in[4];
    const float* b2 = (const float*)d_in[5];
    float* out = (float*)d_out;

    const int n = in_sizes[0] / K;   // 50000
    const int e = in_sizes[1] / 2;   // 800000
    const int nb = (n + 255) / 256;  // 196 buckets

    // workspace layout (8B-aligned head first)
    char* p = (char*)d_ws;
    unsigned long long* tmp = (unsigned long long*)p;  p += (size_t)e * 8;  // (dst,src) pairs
    int* bcnt  = (int*)p;  p += 256 * 4;
    int* bbase = (int*)p;  p += 257 * 4;
    int* gcur  = (int*)p;  p += 256 * 4;
    int* offs  = (int*)p;  p += (size_t)(n + 1) * 4;
    int* srt   = (int*)p;  p += (size_t)e * 4;
    float* dinv = (float*)p;  p += (size_t)n * 4;
    p = (char*)(((uintptr_t)p + 15) & ~(uintptr_t)15);
    unsigned short* G1 = (unsigned short*)p;  p += (size_t)n * 128 * 2;  // bf16 [n][128]
    p = (char*)(((uintptr_t)p + 15) & ~(uintptr_t)15);
    float* H = (float*)p;  p += (size_t)n * 128 * 4;                     // fp32 [n][128]
    p = (char*)(((uintptr_t)p + 15) & ~(uintptr_t)15);
    unsigned short* G2 = (unsigned short*)p;                             // bf16 [n][64]

    // CSR build
    k_zerob<<<1, 256, 0, stream>>>(bcnt);
    k_bcount<<<512, 256, 0, stream>>>(ei + e, e, bcnt, nb);
    k_bscan<<<1, 256, 0, stream>>>(bcnt, bbase, gcur, nb, offs, n, e);
    k_bin<<<(e + 2047) / 2048, 256, 0, stream>>>(ei, e, gcur, tmp);
    k_csr<<<nb, 256, 0, stream>>>(tmp, bbase, offs, srt, dinv, n);

    // Layer 1: H = relu(dinv ⊙ (A_hat G1) + b1), G1 = dinv ⊙ (x@W1)
    k_gemm_mfma<128><<<(n + 63) / 64, 256, 0, stream>>>(x, W1, dinv, G1, n);
    k_reduce128<true><<<(n + 3) / 4, 256, 0, stream>>>(offs, srt, (const uint4*)G1,
                                                       dinv, b1, H, n);

    // Layer 2: out = dinv ⊙ (A_hat G2) + b2, G2 = dinv ⊙ (H@W2)
    k_gemm_mfma<64><<<(n + 63) / 64, 256, 0, stream>>>(H, W2, dinv, G2, n);
    k_reduce64<false><<<(n + 3) / 4, 256, 0, stream>>>(offs, srt, (const uint4*)G2,
                                                       dinv, b2, out, n);
}